// Round 4
// baseline (1028.992 us; speedup 1.0000x reference)
//
#include <hip/hip_runtime.h>
#include <hip/hip_bf16.h>

// GraphNet (NNConv/GRU/Set2Set) forward, MI355X.
// R2: fused single-block head (BN per-column in-register), fused 5-iter
// Set2Set (block-per-graph), k_msg retiled wave->nf (4x less LDS read),
// k_gates with LDS-resident weights.

#define N_  8192
#define E_  32768
#define B_  64
#define D_  64
#define FN_ 32
#define FE_ 16
#define EH_ 128

typedef _Float16 half8 __attribute__((ext_vector_type(8)));
typedef float    f32x4 __attribute__((ext_vector_type(4)));

__device__ __forceinline__ float sigmf(float x) { return 1.f / (1.f + expf(-x)); }

// ---------------- pre: lin0 / BN / edge NN ----------------

__global__ __launch_bounds__(256) void k_lin0(const float* __restrict__ x,
    const float* __restrict__ W, const float* __restrict__ b, float* __restrict__ t0) {
  int gid = blockIdx.x * 256 + threadIdx.x;           // N*64
  int n = gid >> 6, d = gid & 63;
  const float* xr = x + (size_t)n * FN_;
  float a = b[d];
  #pragma unroll
  for (int i = 0; i < FN_; ++i) a += xr[i] * W[i * 64 + d];
  t0[gid] = a;
}

__global__ __launch_bounds__(256) void k_colstats(const float* __restrict__ in, int rows, int cols,
    float* __restrict__ mean, float* __restrict__ rstd) {
  int d = blockIdx.x;
  float s = 0.f, s2 = 0.f;
  for (int n = threadIdx.x; n < rows; n += 256) {
    float v = in[(size_t)n * cols + d];
    s += v; s2 += v * v;
  }
  #pragma unroll
  for (int off = 32; off; off >>= 1) { s += __shfl_xor(s, off); s2 += __shfl_xor(s2, off); }
  __shared__ float ls[4], ls2[4];
  int w = threadIdx.x >> 6;
  if ((threadIdx.x & 63) == 0) { ls[w] = s; ls2[w] = s2; }
  __syncthreads();
  if (threadIdx.x == 0) {
    float S = ls[0] + ls[1] + ls[2] + ls[3], S2 = ls2[0] + ls2[1] + ls2[2] + ls2[3];
    float mu = S / rows;
    float va = S2 / rows - mu * mu;
    mean[d] = mu;
    rstd[d] = rsqrtf(va + 1e-5f);
  }
}

__global__ __launch_bounds__(256) void k_bnrelu0(const float* __restrict__ t0,
    const float* __restrict__ mean, const float* __restrict__ rstd,
    const float* __restrict__ g, const float* __restrict__ b,
    float* __restrict__ x0, float* __restrict__ hb) {
  int gid = blockIdx.x * 256 + threadIdx.x;           // N*64
  int d = gid & 63;
  float v = fmaxf(0.f, (t0[gid] - mean[d]) * rstd[d] * g[d] + b[d]);
  x0[gid] = v; hb[gid] = v;
}

__global__ __launch_bounds__(256) void k_e1(const float* __restrict__ ea,
    const float* __restrict__ W, const float* __restrict__ b, float* __restrict__ t1) {
  int gid = blockIdx.x * 256 + threadIdx.x;           // E*128
  int n = gid >> 7, j = gid & 127;
  const float* er = ea + (size_t)n * FE_;
  float a = b[j];
  #pragma unroll
  for (int i = 0; i < FE_; ++i) a += er[i] * W[i * 128 + j];
  t1[gid] = a;
}

__global__ __launch_bounds__(256) void k_bnrelu_eh(const float* __restrict__ t1,
    const float* __restrict__ mean, const float* __restrict__ rstd,
    const float* __restrict__ g, const float* __restrict__ b, _Float16* __restrict__ ehq) {
  int gid = blockIdx.x * 256 + threadIdx.x;           // E*128
  int d = gid & 127;
  float v = fmaxf(0.f, (t1[gid] - mean[d]) * rstd[d] * g[d] + b[d]);
  ehq[gid] = (_Float16)v;
}

// pack e2_W [128,4096] f32 -> fragment-ready f16: idx (((i*4+kf)*4+nf)*64+lane)*8+j
__global__ __launch_bounds__(256) void k_w2pack(const float* __restrict__ e2W, half8* __restrict__ w2p8) {
  int t = blockIdx.x * 256 + threadIdx.x;             // 65536
  int l = t & 63, nf = (t >> 6) & 3, kf = (t >> 8) & 3, i = t >> 10;
  half8 v;
  #pragma unroll
  for (int j = 0; j < 8; ++j) {
    int k = kf * 32 + ((l >> 4) << 3) + j;
    v[j] = (_Float16)e2W[(size_t)k * 4096 + i * 64 + (nf << 4) + (l & 15)];
  }
  w2p8[t] = v;
}

// ---------------- CSR build (deterministic aggregation) ----------------

__global__ __launch_bounds__(256) void k_cnt(const int* __restrict__ dstI, int* __restrict__ cnt) {
  int e = blockIdx.x * 256 + threadIdx.x;
  atomicAdd(&cnt[dstI[e]], 1);
}

__global__ __launch_bounds__(256) void k_nodecnt(const int* __restrict__ batch, int* __restrict__ nc) {
  int n = blockIdx.x * 256 + threadIdx.x;
  atomicAdd(&nc[batch[n]], 1);
}

__global__ __launch_bounds__(1024) void k_scan(const int* __restrict__ cnt, int* __restrict__ row_start,
    int* __restrict__ cursor, float* __restrict__ cntf) {
  __shared__ int sp[1024];
  int t = threadIdx.x;
  int v[8]; int s = 0;
  #pragma unroll
  for (int j = 0; j < 8; ++j) { v[j] = cnt[t * 8 + j]; s += v[j]; }
  sp[t] = s;
  __syncthreads();
  for (int off = 1; off < 1024; off <<= 1) {
    int a = (t >= off) ? sp[t - off] : 0;
    __syncthreads();
    sp[t] += a;
    __syncthreads();
  }
  int run = sp[t] - s;                                 // exclusive prefix
  #pragma unroll
  for (int j = 0; j < 8; ++j) {
    row_start[t * 8 + j] = run;
    cursor[t * 8 + j] = run;
    cntf[t * 8 + j] = fmaxf(1.0f, (float)v[j]);
    run += v[j];
  }
  if (t == 1023) row_start[N_] = run;                  // = E
}

__global__ void k_gs(const int* __restrict__ nc, int* __restrict__ gs) {
  if (threadIdx.x == 0 && blockIdx.x == 0) {
    int a = 0;
    for (int b = 0; b < B_; ++b) { gs[b] = a; a += nc[b]; }
    gs[B_] = a;
  }
}

__global__ __launch_bounds__(256) void k_fill(const int* __restrict__ dstI, int* __restrict__ cursor,
    int* __restrict__ csr) {
  int e = blockIdx.x * 256 + threadIdx.x;
  int pos = atomicAdd(&cursor[dstI[e]], 1);
  csr[pos] = e;
}

// ---------------- per-step kernels ----------------

// P2 = xo @ reshape(e2_b,64,64); R = xo @ root_W + root_b
__global__ __launch_bounds__(256) void k_nodelin(const float* __restrict__ xo,
    const float* __restrict__ e2b, const float* __restrict__ rootW, const float* __restrict__ rootb,
    float* __restrict__ P2, float* __restrict__ R) {
  int gid = blockIdx.x * 256 + threadIdx.x;            // N*64
  int n = gid >> 6, d = gid & 63;
  const float* xr = xo + (size_t)n * 64;
  float ap = 0.f, ar = rootb[d];
  #pragma unroll 8
  for (int i = 0; i < 64; ++i) {
    float xv = xr[i];
    ap += xv * e2b[i * 64 + d];
    ar += xv * rootW[i * 64 + d];
  }
  P2[gid] = ap; R[gid] = ar;
}

// fused message: msg[e,o] = sum_i xs[e,i]*(eh[e,:]@e2_W[:, i*64+o]) + P2[src[e],o]
// block = 256 thr (4 waves), 64 edges/block; wave w owns output cols [w*16,w*16+16)
// for ALL 64 edges -> B-frag ds_reads drop 4x (4 instead of 16 per i per wave).
__global__ __launch_bounds__(256) void k_msg(const _Float16* __restrict__ ehq,
    const half8* __restrict__ w2p8, const float* __restrict__ xo, const float* __restrict__ P2,
    const int* __restrict__ srcI, float* __restrict__ msg) {
  __shared__ half8 bbuf[2][1024];                      // double-buffered B i-slice (2x16KB)
  __shared__ float xs[64][65];                         // gathered xo[src] tile (+pad)
  __shared__ int ssrc[64];
  const int tid = threadIdx.x;
  const int lane = tid & 63;
  const int w = tid >> 6;
  const int be = blockIdx.x * 64;

  if (tid < 64) ssrc[tid] = srcI[be + tid];
  __syncthreads();
  for (int r = w; r < 64; r += 4) xs[r][lane] = xo[(size_t)ssrc[r] * 64 + lane];

  half8 A[4][4];                                       // eh frags: ALL 64 edges (4 row-tiles) x K=128
  #pragma unroll
  for (int rt = 0; rt < 4; ++rt) {
    const _Float16* ap = ehq + (size_t)(be + rt * 16 + (lane & 15)) * 128 + ((lane >> 4) << 3);
    #pragma unroll
    for (int kf = 0; kf < 4; ++kf) A[rt][kf] = *(const half8*)(ap + kf * 32);
  }
  #pragma unroll
  for (int c = 0; c < 4; ++c) bbuf[0][c * 256 + tid] = w2p8[c * 256 + tid];

  f32x4 acc[4] = {{0.f,0.f,0.f,0.f},{0.f,0.f,0.f,0.f},{0.f,0.f,0.f,0.f},{0.f,0.f,0.f,0.f}};
  __syncthreads();

  for (int i = 0; i < 64; ++i) {
    half8 p[4];                                        // prefetch next i-slice to regs
    const int inext = (i < 63) ? i + 1 : 63;
    const half8* gp = w2p8 + (size_t)inext * 1024;
    #pragma unroll
    for (int c = 0; c < 4; ++c) p[c] = gp[c * 256 + tid];

    const half8* bb = bbuf[i & 1];
    half8 Bf[4];                                       // only wave's nf=w column block
    #pragma unroll
    for (int kf = 0; kf < 4; ++kf) Bf[kf] = bb[(kf * 4 + w) * 64 + lane];

    #pragma unroll
    for (int rt = 0; rt < 4; ++rt) {
      f32x4 C = {0.f, 0.f, 0.f, 0.f};
      #pragma unroll
      for (int kf = 0; kf < 4; ++kf)
        C = __builtin_amdgcn_mfma_f32_16x16x32_f16(A[rt][kf], Bf[kf], C, 0, 0, 0);
      const int rbase = rt * 16 + ((lane >> 4) << 2);  // C/D: col=lane&15, row=(lane>>4)*4+r
      #pragma unroll
      for (int r = 0; r < 4; ++r) acc[rt][r] += xs[rbase + r][i] * C[r];
    }
    half8* nb = bbuf[(i + 1) & 1];
    #pragma unroll
    for (int c = 0; c < 4; ++c) nb[c * 256 + tid] = p[c];
    __syncthreads();
  }

  const int col = (w << 4) + (lane & 15);
  #pragma unroll
  for (int rt = 0; rt < 4; ++rt) {
    const int rbase = rt * 16 + ((lane >> 4) << 2);
    #pragma unroll
    for (int r = 0; r < 4; ++r) {
      const int row = rbase + r;
      const int e = be + row;
      const int sn = ssrc[row];
      msg[(size_t)e * 64 + col] = acc[rt][r] + P2[(size_t)sn * 64 + col];
    }
  }
}

// m[n,:] = relu(segsum(msg)/cnt + R[n,:])  (wave per node)
__global__ __launch_bounds__(256) void k_agg(const float* __restrict__ msg, const int* __restrict__ csr,
    const int* __restrict__ row_start, const float* __restrict__ cntf,
    const float* __restrict__ R, float* __restrict__ m) {
  int lane = threadIdx.x & 63;
  int n = blockIdx.x * 4 + (threadIdx.x >> 6);
  int s0 = row_start[n], s1 = row_start[n + 1];
  float acc = 0.f;
  for (int idx = s0; idx < s1; ++idx) {
    int e = csr[idx];
    acc += msg[(size_t)e * 64 + lane];
  }
  m[(size_t)n * 64 + lane] = fmaxf(0.f, acc / cntf[n] + R[(size_t)n * 64 + lane]);
}

// GRU gates with LDS-resident weights: 256 blocks x 32 nodes.
__global__ __launch_bounds__(256) void k_gates(const float* __restrict__ m, const float* __restrict__ h,
    const float* __restrict__ Wih, const float* __restrict__ Whh,
    const float* __restrict__ bih, const float* __restrict__ bhh,
    float* __restrict__ gi, float* __restrict__ gh) {
  __shared__ float sW[64 * 192];                       // 48 KB
  __shared__ float sV[64 * 192];                       // 48 KB
  __shared__ float sm[32 * 64];                        // 8 KB
  __shared__ float sh2[32 * 64];                       // 8 KB
  const int t = threadIdx.x;
  const int n0 = blockIdx.x * 32;
  for (int idx = t; idx < 64 * 192; idx += 256) { sW[idx] = Wih[idx]; sV[idx] = Whh[idx]; }
  for (int idx = t; idx < 32 * 64; idx += 256) {
    sm[idx] = m[(size_t)n0 * 64 + idx];
    sh2[idx] = h[(size_t)n0 * 64 + idx];
  }
  __syncthreads();
  if (t < 192) {
    const float a0 = bih[t], a1 = bhh[t];
    for (int nn = 0; nn < 32; ++nn) {
      float ai = a0, ah = a1;
      #pragma unroll 8
      for (int d = 0; d < 64; ++d) {
        float mv = sm[nn * 64 + d], hv = sh2[nn * 64 + d];
        ai += mv * sW[d * 192 + t];
        ah += hv * sV[d * 192 + t];
      }
      gi[(size_t)(n0 + nn) * 192 + t] = ai;
      gh[(size_t)(n0 + nn) * 192 + t] = ah;
    }
  }
}

__global__ __launch_bounds__(256) void k_update(const float* __restrict__ gi, const float* __restrict__ gh,
    float* __restrict__ h) {
  int gid = blockIdx.x * 256 + threadIdx.x;            // N*64
  int n = gid >> 6, d = gid & 63;
  const float* gin = gi + (size_t)n * 192;
  const float* ghn = gh + (size_t)n * 192;
  float r = sigmf(gin[d] + ghn[d]);
  float z = sigmf(gin[64 + d] + ghn[64 + d]);
  float nn = tanhf(gin[128 + d] + r * ghn[128 + d]);
  h[gid] = (1.f - z) * nn + z * h[gid];
}

// ---------------- Set2Set: all 5 iterations, block-per-graph ----------------

__global__ __launch_bounds__(256) void k_s2s(const float* __restrict__ xo,
    const int* __restrict__ gs,
    const float* __restrict__ Wih, const float* __restrict__ Whh,
    const float* __restrict__ bih, const float* __restrict__ bhh,
    float* __restrict__ qs_g) {
  __shared__ float sqs[128], shl[64], scl[64], sg[256];
  __shared__ float redm[4], ash[4], rsh[4][64];
  const int t = threadIdx.x;
  const int lane = t & 63, w = t >> 6;
  const int b = blockIdx.x;
  if (t < 128) sqs[t] = 0.f;
  if (t < 64) { shl[t] = 0.f; scl[t] = 0.f; }
  __syncthreads();
  const int s0 = gs[b], s1 = gs[b + 1];
  for (int it = 0; it < 5; ++it) {
    // LSTM gates (reads sqs, shl of previous iteration)
    float a = bih[t] + bhh[t];
    #pragma unroll 8
    for (int k = 0; k < 128; ++k) a += sqs[k] * Wih[k * 256 + t];
    #pragma unroll 8
    for (int k = 0; k < 64; ++k)  a += shl[k] * Whh[k * 256 + t];
    sg[t] = a;
    __syncthreads();
    if (t < 64) {
      float i_ = sg[t], f_ = sg[64 + t], g_ = sg[128 + t], o_ = sg[192 + t];
      float c = sigmf(f_) * scl[t] + sigmf(i_) * tanhf(g_);
      scl[t] = c;
      shl[t] = sigmf(o_) * tanhf(c);
    }
    __syncthreads();
    // attention pass 1: per-graph max of e = <xo_n, q>
    float q = shl[lane];
    float mx = -INFINITY;
    for (int n = s0 + w; n < s1; n += 4) {
      float v = xo[(size_t)n * 64 + lane] * q;
      #pragma unroll
      for (int off = 32; off; off >>= 1) v += __shfl_xor(v, off);
      mx = fmaxf(mx, v);
    }
    if (lane == 0) redm[w] = mx;
    __syncthreads();
    float gmax = fmaxf(fmaxf(redm[0], redm[1]), fmaxf(redm[2], redm[3]));
    // pass 2: recompute e, accumulate softmax num/denom
    float asum = 0.f, racc = 0.f;
    for (int n = s0 + w; n < s1; n += 4) {
      float xv = xo[(size_t)n * 64 + lane];
      float v = xv * q;
      #pragma unroll
      for (int off = 32; off; off >>= 1) v += __shfl_xor(v, off);
      float aa = expf(v - gmax);
      asum += aa;
      racc += aa * xv;
    }
    rsh[w][lane] = racc;
    if (lane == 0) ash[w] = asum;
    __syncthreads();
    if (t < 64) {
      float rt_ = rsh[0][t] + rsh[1][t] + rsh[2][t] + rsh[3][t];
      float at = ash[0] + ash[1] + ash[2] + ash[3];
      sqs[t] = shl[t];
      sqs[64 + t] = rt_ / (at + 1e-16f);
    }
    __syncthreads();
  }
  if (t < 128) qs_g[b * 128 + t] = sqs[t];
}

// ---------------- fused head: f1+f2+f3+fo in ONE block ----------------
// thread = output column => full 64-row column in registers => BN stats local.

__global__ __launch_bounds__(256) void k_headF(const float* __restrict__ qs,
    const float* __restrict__ f1W, const float* __restrict__ f1b,
    const float* __restrict__ f1g, const float* __restrict__ f1bt,
    const float* __restrict__ f2W, const float* __restrict__ f2b,
    const float* __restrict__ f2g, const float* __restrict__ f2bt,
    const float* __restrict__ f3W, const float* __restrict__ f3b,
    const float* __restrict__ f3g, const float* __restrict__ f3bt,
    const float* __restrict__ foW, const float* __restrict__ fob,
    float* __restrict__ out) {
  __shared__ float sA[8192];    // 32 KB: qs, then f2 partials, then y2
  __shared__ float sB[16384];   // 64 KB: y1, then f3 partials
  __shared__ float sC[2048];    // 8 KB: y3
  const int t = threadIdx.x;

  for (int idx = t; idx < 64 * 128; idx += 256) sA[idx] = qs[idx];
  __syncthreads();

  // ---- f1: 128 -> 256 ----
  {
    float acc[64];
    #pragma unroll
    for (int r = 0; r < 64; ++r) acc[r] = 0.f;
    for (int k = 0; k < 128; ++k) {
      float wv = f1W[k * 256 + t];
      #pragma unroll
      for (int r = 0; r < 64; ++r) acc[r] += sA[r * 128 + k] * wv;
    }
    float bv = f1b[t];
    float mu = 0.f, s2 = 0.f;
    #pragma unroll
    for (int r = 0; r < 64; ++r) { float v = acc[r] + bv; mu += v; s2 += v * v; }
    mu *= (1.f / 64.f);
    float rs = rsqrtf(s2 * (1.f / 64.f) - mu * mu + 1e-5f);
    float gg = f1g[t], bb = f1bt[t];
    #pragma unroll
    for (int r = 0; r < 64; ++r)
      sB[r * 256 + t] = fmaxf(0.f, (acc[r] + bv - mu) * rs * gg + bb);
  }
  __syncthreads();

  // ---- f2: 256 -> 128, split-K by 2 ----
  {
    const int col = t & 127, half = t >> 7;
    float acc[64];
    #pragma unroll
    for (int r = 0; r < 64; ++r) acc[r] = 0.f;
    for (int k = 0; k < 128; ++k) {
      int kk = half * 128 + k;
      float wv = f2W[kk * 128 + col];
      #pragma unroll
      for (int r = 0; r < 64; ++r) acc[r] += sB[r * 256 + kk] * wv;
    }
    if (half == 1) {
      #pragma unroll
      for (int r = 0; r < 64; ++r) sA[r * 128 + col] = acc[r];
    }
    __syncthreads();
    if (half == 0) {
      #pragma unroll
      for (int r = 0; r < 64; ++r) acc[r] += sA[r * 128 + col];
      float bv = f2b[col];
      float mu = 0.f, s2 = 0.f;
      #pragma unroll
      for (int r = 0; r < 64; ++r) { float v = acc[r] + bv; mu += v; s2 += v * v; }
      mu *= (1.f / 64.f);
      float rs = rsqrtf(s2 * (1.f / 64.f) - mu * mu + 1e-5f);
      float gg = f2g[col], bb = f2bt[col];
      #pragma unroll
      for (int r = 0; r < 64; ++r)
        sA[r * 128 + col] = fmaxf(0.f, (acc[r] + bv - mu) * rs * gg + bb);  // y2
    }
    __syncthreads();
  }

  // ---- f3: 128 -> 32, split-K by 8 ----
  {
    const int col = t & 31, chunk = t >> 5;            // chunk in [0,8)
    float acc[64];
    #pragma unroll
    for (int r = 0; r < 64; ++r) acc[r] = 0.f;
    #pragma unroll
    for (int kl = 0; kl < 16; ++kl) {
      int kk = chunk * 16 + kl;
      float wv = f3W[kk * 32 + col];
      #pragma unroll
      for (int r = 0; r < 64; ++r) acc[r] += sA[r * 128 + kk] * wv;
    }
    #pragma unroll
    for (int r = 0; r < 64; ++r) sB[chunk * 2048 + r * 32 + col] = acc[r];
    __syncthreads();
    if (t < 32) {
      float a2[64];
      #pragma unroll
      for (int r = 0; r < 64; ++r) {
        float v = 0.f;
        #pragma unroll
        for (int c = 0; c < 8; ++c) v += sB[c * 2048 + r * 32 + t];
        a2[r] = v;
      }
      float bv = f3b[t];
      float mu = 0.f, s2 = 0.f;
      #pragma unroll
      for (int r = 0; r < 64; ++r) { float v = a2[r] + bv; mu += v; s2 += v * v; }
      mu *= (1.f / 64.f);
      float rs = rsqrtf(s2 * (1.f / 64.f) - mu * mu + 1e-5f);
      float gg = f3g[t], bb = f3bt[t];
      #pragma unroll
      for (int r = 0; r < 64; ++r)
        sC[r * 32 + t] = fmaxf(0.f, (a2[r] + bv - mu) * rs * gg + bb);
    }
    __syncthreads();
  }

  // ---- fo: 32 -> 1 ----
  if (t < 64) {
    float v = fob[0];
    #pragma unroll
    for (int k = 0; k < 32; ++k) v += sC[t * 32 + k] * foW[k];
    out[t] = v;
  }
}

// ---------------- host ----------------

extern "C" void kernel_launch(void* const* d_in, const int* in_sizes, int n_in,
                              void* d_out, int out_size, void* d_ws, size_t ws_size,
                              hipStream_t stream) {
  (void)in_sizes; (void)n_in; (void)out_size; (void)ws_size;
  const float* x      = (const float*)d_in[0];
  const float* eattr  = (const float*)d_in[1];
  const int*   ei     = (const int*)d_in[2];
  const int*   batch  = (const int*)d_in[3];
  const float* lin0_W = (const float*)d_in[4];
  const float* lin0_b = (const float*)d_in[5];
  const float* bn0_g  = (const float*)d_in[6];
  const float* bn0_b  = (const float*)d_in[7];
  const float* e1_W   = (const float*)d_in[8];
  const float* e1_b   = (const float*)d_in[9];
  const float* ebn_g  = (const float*)d_in[10];
  const float* ebn_b  = (const float*)d_in[11];
  const float* e2_W   = (const float*)d_in[12];
  const float* e2_b   = (const float*)d_in[13];
  const float* root_W = (const float*)d_in[14];
  const float* root_b = (const float*)d_in[15];
  const float* gWih   = (const float*)d_in[16];
  const float* gWhh   = (const float*)d_in[17];
  const float* gbih   = (const float*)d_in[18];
  const float* gbhh   = (const float*)d_in[19];
  const float* lWih   = (const float*)d_in[20];
  const float* lWhh   = (const float*)d_in[21];
  const float* lbih   = (const float*)d_in[22];
  const float* lbhh   = (const float*)d_in[23];
  const float* f1_W   = (const float*)d_in[24];
  const float* f1_b   = (const float*)d_in[25];
  const float* f1_g   = (const float*)d_in[26];
  const float* f1_bt  = (const float*)d_in[27];
  const float* f2_W   = (const float*)d_in[28];
  const float* f2_b   = (const float*)d_in[29];
  const float* f2_g   = (const float*)d_in[30];
  const float* f2_bt  = (const float*)d_in[31];
  const float* f3_W   = (const float*)d_in[32];
  const float* f3_b   = (const float*)d_in[33];
  const float* f3_g   = (const float*)d_in[34];
  const float* f3_bt  = (const float*)d_in[35];
  const float* fo_W   = (const float*)d_in[36];
  const float* fo_b   = (const float*)d_in[37];
  const int* srcI = ei;
  const int* dstI = ei + E_;

  char* base = (char*)d_ws;
  size_t off = 0;
  auto alloc = [&](size_t bytes) -> void* {
    off = (off + 255) & ~(size_t)255;
    void* p = base + off;
    off += bytes;
    return p;
  };
  float* t0    = (float*)alloc((size_t)N_ * 64 * 4);
  float* t1    = (float*)alloc((size_t)E_ * 128 * 4);
  float* x0    = (float*)alloc((size_t)N_ * 64 * 4);
  float* hb    = (float*)alloc((size_t)N_ * 64 * 4);
  _Float16* ehq = (_Float16*)alloc((size_t)E_ * 128 * 2);
  half8* w2p8  = (half8*)alloc((size_t)65536 * 16);
  float* P2    = (float*)alloc((size_t)N_ * 64 * 4);
  float* R     = (float*)alloc((size_t)N_ * 64 * 4);
  float* mbuf  = (float*)alloc((size_t)N_ * 64 * 4);
  float* gi    = (float*)alloc((size_t)N_ * 192 * 4);
  float* gh    = (float*)alloc((size_t)N_ * 192 * 4);
  float* msg   = (float*)alloc((size_t)E_ * 64 * 4);
  int* cnt_i   = (int*)alloc((size_t)N_ * 4);
  int* cursor  = (int*)alloc((size_t)N_ * 4);
  int* row_start = (int*)alloc((size_t)(N_ + 1) * 4);
  int* csr     = (int*)alloc((size_t)E_ * 4);
  float* cntf  = (float*)alloc((size_t)N_ * 4);
  int* nodecnt = (int*)alloc(64 * 4);
  int* gs      = (int*)alloc(65 * 4);
  float* mean0 = (float*)alloc(64 * 4);
  float* rstd0 = (float*)alloc(64 * 4);
  float* meanE = (float*)alloc(128 * 4);
  float* rstdE = (float*)alloc(128 * 4);
  float* qs    = (float*)alloc((size_t)B_ * 128 * 4);

  hipMemsetAsync(cnt_i, 0, (size_t)N_ * 4, stream);
  hipMemsetAsync(nodecnt, 0, 64 * 4, stream);

  // preprocessing
  k_lin0<<<N_ * 64 / 256, 256, 0, stream>>>(x, lin0_W, lin0_b, t0);
  k_colstats<<<64, 256, 0, stream>>>(t0, N_, 64, mean0, rstd0);
  k_bnrelu0<<<N_ * 64 / 256, 256, 0, stream>>>(t0, mean0, rstd0, bn0_g, bn0_b, x0, hb);
  k_e1<<<E_ * 128 / 256, 256, 0, stream>>>(eattr, e1_W, e1_b, t1);
  k_colstats<<<128, 256, 0, stream>>>(t1, E_, 128, meanE, rstdE);
  k_bnrelu_eh<<<E_ * 128 / 256, 256, 0, stream>>>(t1, meanE, rstdE, ebn_g, ebn_b, ehq);
  k_w2pack<<<256, 256, 0, stream>>>(e2_W, w2p8);
  k_cnt<<<E_ / 256, 256, 0, stream>>>(dstI, cnt_i);
  k_nodecnt<<<N_ / 256, 256, 0, stream>>>(batch, nodecnt);
  k_scan<<<1, 1024, 0, stream>>>(cnt_i, row_start, cursor, cntf);
  k_gs<<<1, 1, 0, stream>>>(nodecnt, gs);
  k_fill<<<E_ / 256, 256, 0, stream>>>(dstI, cursor, csr);

  // 4 message passes
  const float* xo = x0;
  for (int s = 0; s < 4; ++s) {
    k_nodelin<<<N_ * 64 / 256, 256, 0, stream>>>(xo, e2_b, root_W, root_b, P2, R);
    k_msg<<<E_ / 64, 256, 0, stream>>>(ehq, w2p8, xo, P2, srcI, msg);
    k_agg<<<N_ / 4, 256, 0, stream>>>(msg, csr, row_start, cntf, R, mbuf);
    k_gates<<<N_ / 32, 256, 0, stream>>>(mbuf, hb, gWih, gWhh, gbih, gbhh, gi, gh);
    k_update<<<N_ * 64 / 256, 256, 0, stream>>>(gi, gh, hb);
    xo = hb;
  }

  // Set2Set (all 5 iterations in one launch; xo = final h = hb)
  k_s2s<<<B_, 256, 0, stream>>>(hb, gs, lWih, lWhh, lbih, lbhh, qs);

  // fused head
  k_headF<<<1, 256, 0, stream>>>(qs, f1_W, f1_b, f1_g, f1_bt,
                                 f2_W, f2_b, f2_g, f2_bt,
                                 f3_W, f3_b, f3_g, f3_bt,
                                 fo_W, fo_b, (float*)d_out);
}

// Round 5
// 825.696 us; speedup vs baseline: 1.2462x; 1.2462x over previous
//
#include <hip/hip_runtime.h>
#include <hip/hip_bf16.h>

// GraphNet (NNConv/GRU/Set2Set) forward, MI355X.
// R4: launch-count 36->19; k_s2s restructured (LDS xo slab, no shfl chains);
// head = 3 grid-parallel fc kernels; k_node fuses agg+gates+update+P2/R.

#define N_  8192
#define E_  32768
#define B_  64
#define D_  64
#define FN_ 32
#define FE_ 16
#define EH_ 128

typedef _Float16 half8 __attribute__((ext_vector_type(8)));
typedef float    f32x4 __attribute__((ext_vector_type(4)));

__device__ __forceinline__ float sigmf(float x) { return 1.f / (1.f + expf(-x)); }

// ---------------- P1: lin0 + e1 + zero counters ----------------

__global__ __launch_bounds__(256) void k_pre1(const float* __restrict__ x,
    const float* __restrict__ lin0W, const float* __restrict__ lin0b,
    const float* __restrict__ ea, const float* __restrict__ e1W, const float* __restrict__ e1b,
    float* __restrict__ t0, float* __restrict__ t1,
    int* __restrict__ cnt_i, int* __restrict__ nodecnt) {
  const int bid = blockIdx.x, t = threadIdx.x;
  if (bid < 2048) {                                    // lin0: N*64
    int gid = bid * 256 + t;
    int n = gid >> 6, d = gid & 63;
    const float* xr = x + (size_t)n * FN_;
    float a = lin0b[d];
    #pragma unroll
    for (int i = 0; i < FN_; ++i) a += xr[i] * lin0W[i * 64 + d];
    t0[gid] = a;
  } else if (bid < 2048 + 16384) {                     // e1: E*128
    int gid = (bid - 2048) * 256 + t;
    int n = gid >> 7, j = gid & 127;
    const float* er = ea + (size_t)n * FE_;
    float a = e1b[j];
    #pragma unroll
    for (int i = 0; i < FE_; ++i) a += er[i] * e1W[i * 128 + j];
    t1[gid] = a;
  } else if (bid < 2048 + 16384 + 32) {                // zero cnt_i
    cnt_i[(bid - 18432) * 256 + t] = 0;
  } else {                                             // zero nodecnt
    if (t < 64) nodecnt[t] = 0;
  }
}

// ---------------- P2: column stats for both BNs ----------------

__global__ __launch_bounds__(256) void k_stats(const float* __restrict__ t0,
    const float* __restrict__ t1, float* __restrict__ mean0, float* __restrict__ rstd0,
    float* __restrict__ meanE, float* __restrict__ rstdE) {
  const int bid = blockIdx.x;
  const float* in; int rows, cols, d; float* mo; float* ro;
  if (bid < 64) { in = t0; rows = N_; cols = 64; d = bid; mo = mean0; ro = rstd0; }
  else { in = t1; rows = E_; cols = 128; d = bid - 64; mo = meanE; ro = rstdE; }
  float s = 0.f, s2 = 0.f;
  for (int n = threadIdx.x; n < rows; n += 256) {
    float v = in[(size_t)n * cols + d];
    s += v; s2 += v * v;
  }
  #pragma unroll
  for (int off = 32; off; off >>= 1) { s += __shfl_xor(s, off); s2 += __shfl_xor(s2, off); }
  __shared__ float ls[4], ls2[4];
  int w = threadIdx.x >> 6;
  if ((threadIdx.x & 63) == 0) { ls[w] = s; ls2[w] = s2; }
  __syncthreads();
  if (threadIdx.x == 0) {
    float S = ls[0] + ls[1] + ls[2] + ls[3], S2 = ls2[0] + ls2[1] + ls2[2] + ls2[3];
    float mu = S / rows;
    float va = S2 / rows - mu * mu;
    mo[d] = mu;
    ro[d] = rsqrtf(va + 1e-5f);
  }
}

// ---------------- P3: bnrelu0 + bnrelu_eh + w2pack ----------------

__global__ __launch_bounds__(256) void k_pre3(const float* __restrict__ t0,
    const float* __restrict__ mean0, const float* __restrict__ rstd0,
    const float* __restrict__ bn0g, const float* __restrict__ bn0b,
    float* __restrict__ x0, float* __restrict__ hb,
    const float* __restrict__ t1, const float* __restrict__ meanE,
    const float* __restrict__ rstdE, const float* __restrict__ ebng,
    const float* __restrict__ ebnb, _Float16* __restrict__ ehq,
    const float* __restrict__ e2W, half8* __restrict__ w2p8) {
  const int bid = blockIdx.x, t = threadIdx.x;
  if (bid < 2048) {                                    // bnrelu0
    int gid = bid * 256 + t;
    int d = gid & 63;
    float v = fmaxf(0.f, (t0[gid] - mean0[d]) * rstd0[d] * bn0g[d] + bn0b[d]);
    x0[gid] = v; hb[gid] = v;
  } else if (bid < 2048 + 16384) {                     // bnrelu_eh
    int gid = (bid - 2048) * 256 + t;
    int d = gid & 127;
    float v = fmaxf(0.f, (t1[gid] - meanE[d]) * rstdE[d] * ebng[d] + ebnb[d]);
    ehq[gid] = (_Float16)v;
  } else {                                             // w2pack: 65536 items
    int tt = (bid - 18432) * 256 + t;
    int l = tt & 63, nf = (tt >> 6) & 3, kf = (tt >> 8) & 3, i = tt >> 10;
    half8 v;
    #pragma unroll
    for (int j = 0; j < 8; ++j) {
      int k = kf * 32 + ((l >> 4) << 3) + j;
      v[j] = (_Float16)e2W[(size_t)k * 4096 + i * 64 + (nf << 4) + (l & 15)];
    }
    w2p8[tt] = v;
  }
}

// ---------------- CSR build ----------------

__global__ __launch_bounds__(256) void k_count(const int* __restrict__ dstI,
    const int* __restrict__ batch, int* __restrict__ cnt_i, int* __restrict__ nodecnt) {
  const int bid = blockIdx.x, t = threadIdx.x;
  if (bid < 128) atomicAdd(&cnt_i[dstI[bid * 256 + t]], 1);
  else atomicAdd(&nodecnt[batch[(bid - 128) * 256 + t]], 1);
}

__global__ __launch_bounds__(1024) void k_scans(const int* __restrict__ cnt,
    const int* __restrict__ nodecnt, int* __restrict__ row_start,
    int* __restrict__ cursor, float* __restrict__ cntf, int* __restrict__ gs) {
  __shared__ int sp[1024];
  int t = threadIdx.x;
  if (t == 0) {                                        // graph offsets (64 adds)
    int a = 0;
    for (int b = 0; b < B_; ++b) { gs[b] = a; a += nodecnt[b]; }
    gs[B_] = a;
  }
  int v[8]; int s = 0;
  #pragma unroll
  for (int j = 0; j < 8; ++j) { v[j] = cnt[t * 8 + j]; s += v[j]; }
  sp[t] = s;
  __syncthreads();
  for (int off = 1; off < 1024; off <<= 1) {
    int a = (t >= off) ? sp[t - off] : 0;
    __syncthreads();
    sp[t] += a;
    __syncthreads();
  }
  int run = sp[t] - s;
  #pragma unroll
  for (int j = 0; j < 8; ++j) {
    row_start[t * 8 + j] = run;
    cursor[t * 8 + j] = run;
    cntf[t * 8 + j] = fmaxf(1.0f, (float)v[j]);
    run += v[j];
  }
  if (t == 1023) row_start[N_] = run;
}

__global__ __launch_bounds__(256) void k_fill(const int* __restrict__ dstI, int* __restrict__ cursor,
    int* __restrict__ csr) {
  int e = blockIdx.x * 256 + threadIdx.x;
  int pos = atomicAdd(&cursor[dstI[e]], 1);
  csr[pos] = e;
}

// ---------------- step kernels ----------------

// P2 = xo @ reshape(e2_b,64,64); R = xo @ root_W + root_b   (step-0 only)
__global__ __launch_bounds__(256) void k_nodelin(const float* __restrict__ xo,
    const float* __restrict__ e2b, const float* __restrict__ rootW, const float* __restrict__ rootb,
    float* __restrict__ P2, float* __restrict__ R) {
  int gid = blockIdx.x * 256 + threadIdx.x;
  int n = gid >> 6, d = gid & 63;
  const float* xr = xo + (size_t)n * 64;
  float ap = 0.f, ar = rootb[d];
  #pragma unroll 8
  for (int i = 0; i < 64; ++i) {
    float xv = xr[i];
    ap += xv * e2b[i * 64 + d];
    ar += xv * rootW[i * 64 + d];
  }
  P2[gid] = ap; R[gid] = ar;
}

// fused message GEMM (unchanged from R2 — verified)
__global__ __launch_bounds__(256) void k_msg(const _Float16* __restrict__ ehq,
    const half8* __restrict__ w2p8, const float* __restrict__ xo, const float* __restrict__ P2,
    const int* __restrict__ srcI, float* __restrict__ msg) {
  __shared__ half8 bbuf[2][1024];
  __shared__ float xs[64][65];
  __shared__ int ssrc[64];
  const int tid = threadIdx.x;
  const int lane = tid & 63;
  const int w = tid >> 6;
  const int be = blockIdx.x * 64;

  if (tid < 64) ssrc[tid] = srcI[be + tid];
  __syncthreads();
  for (int r = w; r < 64; r += 4) xs[r][lane] = xo[(size_t)ssrc[r] * 64 + lane];

  half8 A[4][4];
  #pragma unroll
  for (int rt = 0; rt < 4; ++rt) {
    const _Float16* ap = ehq + (size_t)(be + rt * 16 + (lane & 15)) * 128 + ((lane >> 4) << 3);
    #pragma unroll
    for (int kf = 0; kf < 4; ++kf) A[rt][kf] = *(const half8*)(ap + kf * 32);
  }
  #pragma unroll
  for (int c = 0; c < 4; ++c) bbuf[0][c * 256 + tid] = w2p8[c * 256 + tid];

  f32x4 acc[4] = {{0.f,0.f,0.f,0.f},{0.f,0.f,0.f,0.f},{0.f,0.f,0.f,0.f},{0.f,0.f,0.f,0.f}};
  __syncthreads();

  for (int i = 0; i < 64; ++i) {
    half8 p[4];
    const int inext = (i < 63) ? i + 1 : 63;
    const half8* gp = w2p8 + (size_t)inext * 1024;
    #pragma unroll
    for (int c = 0; c < 4; ++c) p[c] = gp[c * 256 + tid];

    const half8* bb = bbuf[i & 1];
    half8 Bf[4];
    #pragma unroll
    for (int kf = 0; kf < 4; ++kf) Bf[kf] = bb[(kf * 4 + w) * 64 + lane];

    #pragma unroll
    for (int rt = 0; rt < 4; ++rt) {
      f32x4 C = {0.f, 0.f, 0.f, 0.f};
      #pragma unroll
      for (int kf = 0; kf < 4; ++kf)
        C = __builtin_amdgcn_mfma_f32_16x16x32_f16(A[rt][kf], Bf[kf], C, 0, 0, 0);
      const int rbase = rt * 16 + ((lane >> 4) << 2);
      #pragma unroll
      for (int r = 0; r < 4; ++r) acc[rt][r] += xs[rbase + r][i] * C[r];
    }
    half8* nb = bbuf[(i + 1) & 1];
    #pragma unroll
    for (int c = 0; c < 4; ++c) nb[c * 256 + tid] = p[c];
    __syncthreads();
  }

  const int col = (w << 4) + (lane & 15);
  #pragma unroll
  for (int rt = 0; rt < 4; ++rt) {
    const int rbase = rt * 16 + ((lane >> 4) << 2);
    #pragma unroll
    for (int r = 0; r < 4; ++r) {
      const int row = rbase + r;
      const int e = be + row;
      const int sn = ssrc[row];
      msg[(size_t)e * 64 + col] = acc[rt][r] + P2[(size_t)sn * 64 + col];
    }
  }
}

// fused node update: agg + GRU gates + h update + next-step P2/R. 32 nodes/block.
__global__ __launch_bounds__(256) void k_node(const float* __restrict__ msg,
    const int* __restrict__ csr, const int* __restrict__ row_start,
    const float* __restrict__ cntf,
    const float* __restrict__ Wih, const float* __restrict__ Whh,
    const float* __restrict__ bih, const float* __restrict__ bhh,
    const float* __restrict__ e2b, const float* __restrict__ rootW,
    const float* __restrict__ rootb,
    float* __restrict__ h, float* __restrict__ P2, float* __restrict__ R) {
  __shared__ float sW[64 * 192];                       // 48 KB (reused for e2b/rootW/rootb)
  __shared__ float sV[64 * 192];                       // 48 KB
  __shared__ float sm[32 * 64];                        // 8 KB
  __shared__ float sh[32 * 64];                        // 8 KB
  __shared__ float sgi[8 * 192];                       // 6 KB
  __shared__ float sgh[8 * 192];                       // 6 KB
  const int t = threadIdx.x;
  const int lane = t & 63, w = t >> 6;
  const int n0 = blockIdx.x * 32;

  for (int idx = t; idx < 64 * 192; idx += 256) { sW[idx] = Wih[idx]; sV[idx] = Whh[idx]; }
  // agg (+ stage h): wave per node, 8 rounds
  for (int g = 0; g < 8; ++g) {
    int nl = g * 4 + w;
    int n = n0 + nl;
    int e0 = row_start[n], e1 = row_start[n + 1];
    float acc = 0.f;
    for (int idx = e0; idx < e1; ++idx) acc += msg[(size_t)csr[idx] * 64 + lane];
    sm[nl * 64 + lane] = fmaxf(0.f, acc / cntf[n] + R[(size_t)n * 64 + lane]);
    sh[nl * 64 + lane] = h[(size_t)n * 64 + lane];
  }
  __syncthreads();

  const float bi = (t < 192) ? bih[t] : 0.f;
  const float bh = (t < 192) ? bhh[t] : 0.f;
  for (int c = 0; c < 4; ++c) {                        // chunks of 8 nodes
    const int c8 = c * 8;
    if (t < 192) {
      float ai[8], ah[8];
      #pragma unroll
      for (int j = 0; j < 8; ++j) { ai[j] = bi; ah[j] = bh; }
      for (int d = 0; d < 64; ++d) {
        float wv = sW[d * 192 + t], vv = sV[d * 192 + t];
        #pragma unroll
        for (int j = 0; j < 8; ++j) {
          ai[j] += sm[(c8 + j) * 64 + d] * wv;
          ah[j] += sh[(c8 + j) * 64 + d] * vv;
        }
      }
      #pragma unroll
      for (int j = 0; j < 8; ++j) { sgi[j * 192 + t] = ai[j]; sgh[j * 192 + t] = ah[j]; }
    }
    __syncthreads();
    #pragma unroll
    for (int rep = 0; rep < 2; ++rep) {
      int idx = rep * 256 + t;
      int j = idx >> 6, d = idx & 63;
      int nl = c8 + j;
      float r = sigmf(sgi[j * 192 + d] + sgh[j * 192 + d]);
      float z = sigmf(sgi[j * 192 + 64 + d] + sgh[j * 192 + 64 + d]);
      float nn = tanhf(sgi[j * 192 + 128 + d] + r * sgh[j * 192 + 128 + d]);
      float hv = (1.f - z) * nn + z * sh[nl * 64 + d];
      sh[nl * 64 + d] = hv;
      h[(size_t)(n0 + nl) * 64 + d] = hv;
    }
    __syncthreads();
  }

  // next-step P2/R from updated h (reuse sW)
  for (int idx = t; idx < 4096; idx += 256) { sW[idx] = e2b[idx]; sW[4096 + idx] = rootW[idx]; }
  if (t < 64) sW[8192 + t] = rootb[t];
  __syncthreads();
  for (int g = 0; g < 8; ++g) {
    int nl = g * 4 + w;
    float ap = 0.f, ar = sW[8192 + lane];
    #pragma unroll 8
    for (int i = 0; i < 64; ++i) {
      float hv = sh[nl * 64 + i];
      ap += hv * sW[i * 64 + lane];
      ar += hv * sW[4096 + i * 64 + lane];
    }
    P2[(size_t)(n0 + nl) * 64 + lane] = ap;
    R[(size_t)(n0 + nl) * 64 + lane] = ar;
  }
}

// ---------------- Set2Set: 5 iterations, block-per-graph, no shfl chains ----------------

#define SCAP 224

__global__ __launch_bounds__(256) void k_s2s(const float* __restrict__ xo,
    const int* __restrict__ gs,
    const float* __restrict__ Wih, const float* __restrict__ Whh,
    const float* __restrict__ bih, const float* __restrict__ bhh,
    float* __restrict__ qs_g) {
  __shared__ float sxo[SCAP * 65];                     // xo slab (padded, conflict-free)
  __shared__ float sqs[128], shl[64], scl[64], sg[256];
  __shared__ float se[512];
  __shared__ float redm[4], ash[4], rsh[4][64];
  const int t = threadIdx.x;
  const int lane = t & 63, w = t >> 6;
  const int b = blockIdx.x;
  const int s0 = gs[b], cnt = gs[b + 1] - s0;
  const int cc = (cnt < SCAP) ? cnt : SCAP;

  for (int i = w; i < cc; i += 4) sxo[i * 65 + lane] = xo[(size_t)(s0 + i) * 64 + lane];
  if (t < 128) sqs[t] = 0.f;
  if (t < 64) { shl[t] = 0.f; scl[t] = 0.f; }
  __syncthreads();

  for (int it = 0; it < 5; ++it) {
    // LSTM gates
    float a = bih[t] + bhh[t];
    #pragma unroll 8
    for (int k = 0; k < 128; ++k) a += sqs[k] * Wih[k * 256 + t];
    #pragma unroll 8
    for (int k = 0; k < 64; ++k)  a += shl[k] * Whh[k * 256 + t];
    sg[t] = a;
    __syncthreads();
    if (t < 64) {
      float i_ = sg[t], f_ = sg[64 + t], g_ = sg[128 + t], o_ = sg[192 + t];
      float cl = sigmf(f_) * scl[t] + sigmf(i_) * tanhf(g_);
      scl[t] = cl;
      shl[t] = sigmf(o_) * tanhf(cl);
    }
    __syncthreads();
    // e[n] = <xo_n, q>: thread-per-node (no cross-lane)
    for (int i = t; i < cnt; i += 256) {
      float acc = 0.f;
      if (i < SCAP) {
        #pragma unroll 8
        for (int d = 0; d < 64; ++d) acc += sxo[i * 65 + d] * shl[d];
      } else {
        const float* xr = xo + (size_t)(s0 + i) * 64;
        #pragma unroll 8
        for (int d = 0; d < 64; ++d) acc += xr[d] * shl[d];
      }
      se[i] = acc;
    }
    __syncthreads();
    // graph max
    float mx = -INFINITY;
    for (int i = t; i < cnt; i += 256) mx = fmaxf(mx, se[i]);
    #pragma unroll
    for (int off = 32; off; off >>= 1) mx = fmaxf(mx, __shfl_xor(mx, off));
    if (lane == 0) redm[w] = mx;
    __syncthreads();
    const float gmax = fmaxf(fmaxf(redm[0], redm[1]), fmaxf(redm[2], redm[3]));
    // exp + sum (se := a)
    float s = 0.f;
    for (int i = t; i < cnt; i += 256) {
      float aa = expf(se[i] - gmax);
      se[i] = aa;
      s += aa;
    }
    #pragma unroll
    for (int off = 32; off; off >>= 1) s += __shfl_xor(s, off);
    if (lane == 0) ash[w] = s;
    __syncthreads();
    const float gsum = ash[0] + ash[1] + ash[2] + ash[3];
    // rsum[d]: lane-per-dim, coalesced
    float racc = 0.f;
    for (int i = w; i < cnt; i += 4) {
      float aa = se[i];
      racc += (i < SCAP) ? aa * sxo[i * 65 + lane]
                         : aa * xo[(size_t)(s0 + i) * 64 + lane];
    }
    rsh[w][lane] = racc;
    __syncthreads();
    if (t < 64) {
      float rt_ = rsh[0][t] + rsh[1][t] + rsh[2][t] + rsh[3][t];
      sqs[t] = shl[t];
      sqs[64 + t] = rt_ / (gsum + 1e-16f);
    }
    __syncthreads();
  }
  if (t < 128) qs_g[b * 128 + t] = sqs[t];
}

// ---------------- head: wave-per-column fc + BN ----------------

__global__ __launch_bounds__(256) void k_fc(const float* __restrict__ in,
    const float* __restrict__ W, const float* __restrict__ bias,
    const float* __restrict__ g, const float* __restrict__ bt,
    float* __restrict__ out, int K, int NC) {
  __shared__ float sin_[64 * 257];
  const int t = threadIdx.x, lane = t & 63, w = t >> 6;
  const int c = blockIdx.x * 4 + w;
  const int Kp = K + 1;
  for (int idx = t; idx < 64 * K; idx += 256) sin_[(idx / K) * Kp + (idx % K)] = in[idx];
  __syncthreads();
  float acc = 0.f;
  const float* wc = W + c;
  #pragma unroll 8
  for (int k = 0; k < K; ++k) acc += sin_[lane * Kp + k] * wc[(size_t)k * NC];
  acc += bias[c];
  float s = acc, s2 = acc * acc;
  #pragma unroll
  for (int off = 32; off; off >>= 1) { s += __shfl_xor(s, off); s2 += __shfl_xor(s2, off); }
  float mu = s * (1.f / 64.f);
  float rs = rsqrtf(s2 * (1.f / 64.f) - mu * mu + 1e-5f);
  out[(size_t)lane * NC + c] = fmaxf(0.f, (acc - mu) * rs * g[c] + bt[c]);
}

__global__ __launch_bounds__(256) void k_f3fo(const float* __restrict__ y2,
    const float* __restrict__ f3W, const float* __restrict__ f3b,
    const float* __restrict__ f3g, const float* __restrict__ f3bt,
    const float* __restrict__ foW, const float* __restrict__ fob,
    float* __restrict__ out) {
  __shared__ float sin_[64 * 129];
  __shared__ float sy3[64 * 33];
  const int t = threadIdx.x, lane = t & 63, w = t >> 6;
  for (int idx = t; idx < 64 * 128; idx += 256) sin_[(idx >> 7) * 129 + (idx & 127)] = y2[idx];
  __syncthreads();
  #pragma unroll
  for (int cg = 0; cg < 8; ++cg) {
    int c = w * 8 + cg;
    float acc = 0.f;
    #pragma unroll 8
    for (int k = 0; k < 128; ++k) acc += sin_[lane * 129 + k] * f3W[k * 32 + c];
    acc += f3b[c];
    float s = acc, s2 = acc * acc;
    #pragma unroll
    for (int off = 32; off; off >>= 1) { s += __shfl_xor(s, off); s2 += __shfl_xor(s2, off); }
    float mu = s * (1.f / 64.f);
    float rs = rsqrtf(s2 * (1.f / 64.f) - mu * mu + 1e-5f);
    sy3[lane * 33 + c] = fmaxf(0.f, (acc - mu) * rs * f3g[c] + f3bt[c]);
  }
  __syncthreads();
  if (t < 64) {
    float v = fob[0];
    #pragma unroll
    for (int k = 0; k < 32; ++k) v += sy3[t * 33 + k] * foW[k];
    out[t] = v;
  }
}

// ---------------- host ----------------

extern "C" void kernel_launch(void* const* d_in, const int* in_sizes, int n_in,
                              void* d_out, int out_size, void* d_ws, size_t ws_size,
                              hipStream_t stream) {
  (void)in_sizes; (void)n_in; (void)out_size; (void)ws_size;
  const float* x      = (const float*)d_in[0];
  const float* eattr  = (const float*)d_in[1];
  const int*   ei     = (const int*)d_in[2];
  const int*   batch  = (const int*)d_in[3];
  const float* lin0_W = (const float*)d_in[4];
  const float* lin0_b = (const float*)d_in[5];
  const float* bn0_g  = (const float*)d_in[6];
  const float* bn0_b  = (const float*)d_in[7];
  const float* e1_W   = (const float*)d_in[8];
  const float* e1_b   = (const float*)d_in[9];
  const float* ebn_g  = (const float*)d_in[10];
  const float* ebn_b  = (const float*)d_in[11];
  const float* e2_W   = (const float*)d_in[12];
  const float* e2_b   = (const float*)d_in[13];
  const float* root_W = (const float*)d_in[14];
  const float* root_b = (const float*)d_in[15];
  const float* gWih   = (const float*)d_in[16];
  const float* gWhh   = (const float*)d_in[17];
  const float* gbih   = (const float*)d_in[18];
  const float* gbhh   = (const float*)d_in[19];
  const float* lWih   = (const float*)d_in[20];
  const float* lWhh   = (const float*)d_in[21];
  const float* lbih   = (const float*)d_in[22];
  const float* lbhh   = (const float*)d_in[23];
  const float* f1_W   = (const float*)d_in[24];
  const float* f1_b   = (const float*)d_in[25];
  const float* f1_g   = (const float*)d_in[26];
  const float* f1_bt  = (const float*)d_in[27];
  const float* f2_W   = (const float*)d_in[28];
  const float* f2_b   = (const float*)d_in[29];
  const float* f2_g   = (const float*)d_in[30];
  const float* f2_bt  = (const float*)d_in[31];
  const float* f3_W   = (const float*)d_in[32];
  const float* f3_b   = (const float*)d_in[33];
  const float* f3_g   = (const float*)d_in[34];
  const float* f3_bt  = (const float*)d_in[35];
  const float* fo_W   = (const float*)d_in[36];
  const float* fo_b   = (const float*)d_in[37];
  const int* srcI = ei;
  const int* dstI = ei + E_;

  char* base = (char*)d_ws;
  size_t off = 0;
  auto alloc = [&](size_t bytes) -> void* {
    off = (off + 255) & ~(size_t)255;
    void* p = base + off;
    off += bytes;
    return p;
  };
  float* t0    = (float*)alloc((size_t)N_ * 64 * 4);
  float* t1    = (float*)alloc((size_t)E_ * 128 * 4);
  float* x0    = (float*)alloc((size_t)N_ * 64 * 4);
  float* hb    = (float*)alloc((size_t)N_ * 64 * 4);
  _Float16* ehq = (_Float16*)alloc((size_t)E_ * 128 * 2);
  half8* w2p8  = (half8*)alloc((size_t)65536 * 16);
  float* P2    = (float*)alloc((size_t)N_ * 64 * 4);
  float* R     = (float*)alloc((size_t)N_ * 64 * 4);
  float* msg   = (float*)alloc((size_t)E_ * 64 * 4);
  int* cnt_i   = (int*)alloc((size_t)N_ * 4);
  int* cursor  = (int*)alloc((size_t)N_ * 4);
  int* row_start = (int*)alloc((size_t)(N_ + 1) * 4);
  int* csr     = (int*)alloc((size_t)E_ * 4);
  float* cntf  = (float*)alloc((size_t)N_ * 4);
  int* nodecnt = (int*)alloc(64 * 4);
  int* gs      = (int*)alloc(65 * 4);
  float* mean0 = (float*)alloc(64 * 4);
  float* rstd0 = (float*)alloc(64 * 4);
  float* meanE = (float*)alloc(128 * 4);
  float* rstdE = (float*)alloc(128 * 4);
  float* qs    = (float*)alloc((size_t)B_ * 128 * 4);
  float* y1    = (float*)alloc((size_t)B_ * 256 * 4);
  float* y2    = (float*)alloc((size_t)B_ * 128 * 4);

  // pre (3) + csr (3)
  k_pre1<<<18465, 256, 0, stream>>>(x, lin0_W, lin0_b, eattr, e1_W, e1_b, t0, t1, cnt_i, nodecnt);
  k_stats<<<192, 256, 0, stream>>>(t0, t1, mean0, rstd0, meanE, rstdE);
  k_pre3<<<18688, 256, 0, stream>>>(t0, mean0, rstd0, bn0_g, bn0_b, x0, hb,
                                    t1, meanE, rstdE, ebn_g, ebn_b, ehq, e2_W, w2p8);
  k_count<<<160, 256, 0, stream>>>(dstI, batch, cnt_i, nodecnt);
  k_scans<<<1, 1024, 0, stream>>>(cnt_i, nodecnt, row_start, cursor, cntf, gs);
  k_fill<<<E_ / 256, 256, 0, stream>>>(dstI, cursor, csr);

  // step-0 P2/R
  k_nodelin<<<N_ * 64 / 256, 256, 0, stream>>>(x0, e2_b, root_W, root_b, P2, R);

  // 4 message passes: msg reads P2; node consumes R, writes h and next P2/R
  for (int s = 0; s < 4; ++s) {
    k_msg<<<E_ / 64, 256, 0, stream>>>(ehq, w2p8, (s == 0) ? x0 : hb, P2, srcI, msg);
    k_node<<<N_ / 32, 256, 0, stream>>>(msg, csr, row_start, cntf,
                                        gWih, gWhh, gbih, gbhh,
                                        e2_b, root_W, root_b, hb, P2, R);
  }

  // Set2Set + head
  k_s2s<<<B_, 256, 0, stream>>>(hb, gs, lWih, lWhh, lbih, lbhh, qs);
  k_fc<<<64, 256, 0, stream>>>(qs, f1_W, f1_b, f1_g, f1_bt, y1, 128, 256);
  k_fc<<<32, 256, 0, stream>>>(y1, f2_W, f2_b, f2_g, f2_bt, y2, 256, 128);
  k_f3fo<<<1, 256, 0, stream>>>(y2, f3_W, f3_b, f3_g, f3_bt, fo_W, fo_b, (float*)d_out);
}

// Round 9
// 668.263 us; speedup vs baseline: 1.5398x; 1.2356x over previous
//
#include <hip/hip_runtime.h>
#include <hip/hip_bf16.h>

// GraphNet (NNConv/GRU/Set2Set) forward, MI355X.
// R5: k_node rebuilt on MFMA (gates + P2/R GEMMs), LDS 124KB->35KB, 512 blocks;
// k_msg staging via global_load_lds; count folded into pre1, nodelin into fill.

#define N_  8192
#define E_  32768
#define B_  64
#define D_  64
#define FN_ 32
#define FE_ 16
#define EH_ 128

typedef _Float16 half8 __attribute__((ext_vector_type(8)));
typedef float    f32x4 __attribute__((ext_vector_type(4)));

__device__ __forceinline__ float sigmf(float x) { return 1.f / (1.f + expf(-x)); }

#if __has_builtin(__builtin_amdgcn_global_load_lds)
#define HAVE_GLDS 1
__device__ __forceinline__ void gl2lds16(const void* g, void* l) {
  __builtin_amdgcn_global_load_lds(
      (const __attribute__((address_space(1))) void*)g,
      (__attribute__((address_space(3))) void*)l, 16, 0, 0);
}
#else
#define HAVE_GLDS 0
#endif

// ---------------- P1: lin0 + e1 + degree/graph counting ----------------

__global__ __launch_bounds__(256) void k_pre1(const float* __restrict__ x,
    const float* __restrict__ lin0W, const float* __restrict__ lin0b,
    const float* __restrict__ ea, const float* __restrict__ e1W, const float* __restrict__ e1b,
    const int* __restrict__ dstI, const int* __restrict__ batch,
    float* __restrict__ t0, float* __restrict__ t1,
    int* __restrict__ cnt_i, int* __restrict__ nodecnt) {
  const int bid = blockIdx.x, t = threadIdx.x;
  if (bid < 2048) {                                    // lin0: N*64
    int gid = bid * 256 + t;
    int n = gid >> 6, d = gid & 63;
    const float* xr = x + (size_t)n * FN_;
    float a = lin0b[d];
    #pragma unroll
    for (int i = 0; i < FN_; ++i) a += xr[i] * lin0W[i * 64 + d];
    t0[gid] = a;
  } else if (bid < 18432) {                            // e1: E*128
    int gid = (bid - 2048) * 256 + t;
    int n = gid >> 7, j = gid & 127;
    const float* er = ea + (size_t)n * FE_;
    float a = e1b[j];
    #pragma unroll
    for (int i = 0; i < FE_; ++i) a += er[i] * e1W[i * 128 + j];
    t1[gid] = a;
  } else if (bid < 18560) {                            // edge degree count
    atomicAdd(&cnt_i[dstI[(bid - 18432) * 256 + t]], 1);
  } else {                                             // graph node count
    atomicAdd(&nodecnt[batch[(bid - 18560) * 256 + t]], 1);
  }
}

// ---------------- P2: column stats for both BNs ----------------

__global__ __launch_bounds__(256) void k_stats(const float* __restrict__ t0,
    const float* __restrict__ t1, float* __restrict__ mean0, float* __restrict__ rstd0,
    float* __restrict__ meanE, float* __restrict__ rstdE) {
  const int bid = blockIdx.x;
  const float* in; int rows, cols, d; float* mo; float* ro;
  if (bid < 64) { in = t0; rows = N_; cols = 64; d = bid; mo = mean0; ro = rstd0; }
  else { in = t1; rows = E_; cols = 128; d = bid - 64; mo = meanE; ro = rstdE; }
  float s = 0.f, s2 = 0.f;
  for (int n = threadIdx.x; n < rows; n += 256) {
    float v = in[(size_t)n * cols + d];
    s += v; s2 += v * v;
  }
  #pragma unroll
  for (int off = 32; off; off >>= 1) { s += __shfl_xor(s, off); s2 += __shfl_xor(s2, off); }
  __shared__ float ls[4], ls2[4];
  int w = threadIdx.x >> 6;
  if ((threadIdx.x & 63) == 0) { ls[w] = s; ls2[w] = s2; }
  __syncthreads();
  if (threadIdx.x == 0) {
    float S = ls[0] + ls[1] + ls[2] + ls[3], S2 = ls2[0] + ls2[1] + ls2[2] + ls2[3];
    float mu = S / rows;
    float va = S2 / rows - mu * mu;
    mo[d] = mu;
    ro[d] = rsqrtf(va + 1e-5f);
  }
}

// ---------------- P3: bnrelu0 + bnrelu_eh + all weight packing ----------------

__global__ __launch_bounds__(256) void k_pre3(const float* __restrict__ t0,
    const float* __restrict__ mean0, const float* __restrict__ rstd0,
    const float* __restrict__ bn0g, const float* __restrict__ bn0b,
    float* __restrict__ x0, float* __restrict__ hb,
    const float* __restrict__ t1, const float* __restrict__ meanE,
    const float* __restrict__ rstdE, const float* __restrict__ ebng,
    const float* __restrict__ ebnb, _Float16* __restrict__ ehq,
    const float* __restrict__ e2W, half8* __restrict__ w2p8,
    const float* __restrict__ gWih, const float* __restrict__ gWhh,
    half8* __restrict__ pWih, half8* __restrict__ pWhh,
    const float* __restrict__ e2b, const float* __restrict__ rootW,
    half8* __restrict__ pE2R) {
  const int bid = blockIdx.x, t = threadIdx.x;
  if (bid < 2048) {                                    // bnrelu0
    int gid = bid * 256 + t;
    int d = gid & 63;
    float v = fmaxf(0.f, (t0[gid] - mean0[d]) * rstd0[d] * bn0g[d] + bn0b[d]);
    x0[gid] = v; hb[gid] = v;
  } else if (bid < 18432) {                            // bnrelu_eh
    int gid = (bid - 2048) * 256 + t;
    int d = gid & 127;
    float v = fmaxf(0.f, (t1[gid] - meanE[d]) * rstdE[d] * ebng[d] + ebnb[d]);
    ehq[gid] = (_Float16)v;
  } else if (bid < 18688) {                            // w2pack: 65536 items
    int tt = (bid - 18432) * 256 + t;
    int l = tt & 63, nf = (tt >> 6) & 3, kf = (tt >> 8) & 3, i = tt >> 10;
    half8 v;
    #pragma unroll
    for (int j = 0; j < 8; ++j) {
      int k = kf * 32 + ((l >> 4) << 3) + j;
      v[j] = (_Float16)e2W[(size_t)k * 4096 + i * 64 + (nf << 4) + (l & 15)];
    }
    w2p8[tt] = v;
  } else if (bid < 18700) {                            // pack gWih/gWhh: 3072 items
    int tt2 = (bid - 18688) * 256 + t;
    int tab = (tt2 >= 1536);
    int rr = tab ? tt2 - 1536 : tt2;
    int lane = rr & 63, q = rr >> 6;
    int tile = q % 12, kf = q / 12;
    const float* W = tab ? gWhh : gWih;
    int col = tile * 16 + (lane & 15);
    half8 v;
    #pragma unroll
    for (int j = 0; j < 8; ++j) {
      int k = kf * 32 + ((lane >> 4) << 3) + j;
      v[j] = (_Float16)W[k * 192 + col];
    }
    (tab ? pWhh : pWih)[rr] = v;
  } else {                                             // pack e2b|rootW: 1024 items
    int rr = (bid - 18700) * 256 + t;
    int lane = rr & 63, q = rr >> 6;
    int tile = q % 8, kf = q / 8;
    int col = tile * 16 + (lane & 15);
    half8 v;
    #pragma unroll
    for (int j = 0; j < 8; ++j) {
      int k = kf * 32 + ((lane >> 4) << 3) + j;
      v[j] = (_Float16)((col < 64) ? e2b[k * 64 + col] : rootW[k * 64 + (col - 64)]);
    }
    pE2R[rr] = v;
  }
}

// ---------------- CSR scan + fill (+ step-0 P2/R) ----------------

__global__ __launch_bounds__(1024) void k_scans(const int* __restrict__ cnt,
    const int* __restrict__ nodecnt, int* __restrict__ row_start,
    int* __restrict__ cursor, float* __restrict__ cntf, int* __restrict__ gs) {
  __shared__ int sp[1024];
  int t = threadIdx.x;
  if (t == 0) {
    int a = 0;
    for (int b = 0; b < B_; ++b) { gs[b] = a; a += nodecnt[b]; }
    gs[B_] = a;
  }
  int v[8]; int s = 0;
  #pragma unroll
  for (int j = 0; j < 8; ++j) { v[j] = cnt[t * 8 + j]; s += v[j]; }
  sp[t] = s;
  __syncthreads();
  for (int off = 1; off < 1024; off <<= 1) {
    int a = (t >= off) ? sp[t - off] : 0;
    __syncthreads();
    sp[t] += a;
    __syncthreads();
  }
  int run = sp[t] - s;
  #pragma unroll
  for (int j = 0; j < 8; ++j) {
    row_start[t * 8 + j] = run;
    cursor[t * 8 + j] = run;
    cntf[t * 8 + j] = fmaxf(1.0f, (float)v[j]);
    run += v[j];
  }
  if (t == 1023) row_start[N_] = run;
}

__global__ __launch_bounds__(256) void k_fillnl(const int* __restrict__ dstI,
    int* __restrict__ cursor, int* __restrict__ csr,
    const float* __restrict__ x0, const float* __restrict__ e2b,
    const float* __restrict__ rootW, const float* __restrict__ rootb,
    float* __restrict__ P2, float* __restrict__ R) {
  const int bid = blockIdx.x, t = threadIdx.x;
  if (bid < 128) {                                     // csr fill
    int e = bid * 256 + t;
    int pos = atomicAdd(&cursor[dstI[e]], 1);
    csr[pos] = e;
  } else {                                             // step-0 P2/R (f32)
    int gid = (bid - 128) * 256 + t;
    int n = gid >> 6, d = gid & 63;
    const float* xr = x0 + (size_t)n * 64;
    float ap = 0.f, ar = rootb[d];
    #pragma unroll 8
    for (int i = 0; i < 64; ++i) {
      float xv = xr[i];
      ap += xv * e2b[i * 64 + d];
      ar += xv * rootW[i * 64 + d];
    }
    P2[gid] = ap; R[gid] = ar;
  }
}

// ---------------- fused message GEMM ----------------

__global__ __launch_bounds__(256) void k_msg(const _Float16* __restrict__ ehq,
    const half8* __restrict__ w2p8, const float* __restrict__ xo, const float* __restrict__ P2,
    const int* __restrict__ srcI, float* __restrict__ msg) {
  __shared__ half8 bbuf[2][1024];
  __shared__ float xs[64][65];
  __shared__ int ssrc[64];
  const int tid = threadIdx.x;
  const int lane = tid & 63;
  const int w = tid >> 6;
  const int be = blockIdx.x * 64;

  if (tid < 64) ssrc[tid] = srcI[be + tid];
#if HAVE_GLDS
  #pragma unroll
  for (int c = 0; c < 4; ++c) gl2lds16(w2p8 + c * 256 + tid, &bbuf[0][c * 256 + tid]);
#endif
  __syncthreads();
  for (int r = w; r < 64; r += 4) xs[r][lane] = xo[(size_t)ssrc[r] * 64 + lane];

  half8 A[4][4];
  #pragma unroll
  for (int rt = 0; rt < 4; ++rt) {
    const _Float16* ap = ehq + (size_t)(be + rt * 16 + (lane & 15)) * 128 + ((lane >> 4) << 3);
    #pragma unroll
    for (int kf = 0; kf < 4; ++kf) A[rt][kf] = *(const half8*)(ap + kf * 32);
  }
#if !HAVE_GLDS
  #pragma unroll
  for (int c = 0; c < 4; ++c) bbuf[0][c * 256 + tid] = w2p8[c * 256 + tid];
#endif

  f32x4 acc[4] = {{0.f,0.f,0.f,0.f},{0.f,0.f,0.f,0.f},{0.f,0.f,0.f,0.f},{0.f,0.f,0.f,0.f}};
  __syncthreads();

  for (int i = 0; i < 64; ++i) {
    const int inext = (i < 63) ? i + 1 : 63;
    const half8* gp = w2p8 + (size_t)inext * 1024;
#if HAVE_GLDS
    half8* nb = &bbuf[(i + 1) & 1][0];
    #pragma unroll
    for (int c = 0; c < 4; ++c) gl2lds16(gp + c * 256 + tid, nb + c * 256 + tid);
#else
    half8 p[4];
    #pragma unroll
    for (int c = 0; c < 4; ++c) p[c] = gp[c * 256 + tid];
#endif

    const half8* bb = bbuf[i & 1];
    half8 Bf[4];
    #pragma unroll
    for (int kf = 0; kf < 4; ++kf) Bf[kf] = bb[(kf * 4 + w) * 64 + lane];

    #pragma unroll
    for (int rt = 0; rt < 4; ++rt) {
      f32x4 C = {0.f, 0.f, 0.f, 0.f};
      #pragma unroll
      for (int kf = 0; kf < 4; ++kf)
        C = __builtin_amdgcn_mfma_f32_16x16x32_f16(A[rt][kf], Bf[kf], C, 0, 0, 0);
      const int rbase = rt * 16 + ((lane >> 4) << 2);
      #pragma unroll
      for (int r = 0; r < 4; ++r) acc[rt][r] += xs[rbase + r][i] * C[r];
    }
#if !HAVE_GLDS
    half8* nb = &bbuf[(i + 1) & 1][0];
    #pragma unroll
    for (int c = 0; c < 4; ++c) nb[c * 256 + tid] = p[c];
#endif
    __syncthreads();
  }

  const int col = (w << 4) + (lane & 15);
  #pragma unroll
  for (int rt = 0; rt < 4; ++rt) {
    const int rbase = rt * 16 + ((lane >> 4) << 2);
    #pragma unroll
    for (int r = 0; r < 4; ++r) {
      const int row = rbase + r;
      const int e = be + row;
      const int sn = ssrc[row];
      msg[(size_t)e * 64 + col] = acc[rt][r] + P2[(size_t)sn * 64 + col];
    }
  }
}

// ---------------- fused node update (MFMA): agg + GRU + P2/R. 16 nodes/block ----------------

__global__ __launch_bounds__(256) void k_node(const float* __restrict__ msg,
    const int* __restrict__ csr, const int* __restrict__ row_start,
    const float* __restrict__ cntf,
    const half8* __restrict__ pWih, const half8* __restrict__ pWhh,
    const float* __restrict__ bih, const float* __restrict__ bhh,
    const half8* __restrict__ pE2R, const float* __restrict__ rootb,
    float* __restrict__ h, float* __restrict__ P2, float* __restrict__ R, int doPR) {
  __shared__ _Float16 sm16[16 * 72];                   // m (f16, padded: 2-way free)
  __shared__ _Float16 sh16[16 * 72];                   // h old->new (f16)
  __shared__ float sh32[16 * 64];                      // h old (f32)
  __shared__ float sgi[16 * 208];                      // gi (stride 208: 2-way free)
  __shared__ float sgh[16 * 208];
  const int t = threadIdx.x, lane = t & 63, w = t >> 6;
  const int n0 = blockIdx.x * 16;

  // A: aggregate + stage h
  #pragma unroll
  for (int g = 0; g < 4; ++g) {
    int nl = g * 4 + w, n = n0 + nl;
    int e0 = row_start[n], e1 = row_start[n + 1];
    float acc = 0.f;
    for (int idx = e0; idx < e1; ++idx) acc += msg[(size_t)csr[idx] * 64 + lane];
    float mval = fmaxf(0.f, acc / cntf[n] + R[(size_t)n * 64 + lane]);
    float hval = h[(size_t)n * 64 + lane];
    sm16[nl * 72 + lane] = (_Float16)mval;
    sh16[nl * 72 + lane] = (_Float16)hval;
    sh32[nl * 64 + lane] = hval;
  }
  __syncthreads();

  // B: gate GEMMs via MFMA. waves 0-1: gi = m@Wih; waves 2-3: gh = h@Whh.
  {
    const _Float16* As = (w < 2) ? sm16 : sh16;
    const half8* pW = (w < 2) ? pWih : pWhh;
    float* sg_ = (w < 2) ? sgi : sgh;
    const int abase = (lane & 15) * 72 + ((lane >> 4) << 3);
    half8 A0 = *(const half8*)(As + abase);
    half8 A1 = *(const half8*)(As + abase + 32);
    const int tbase = (w & 1) * 6;
    #pragma unroll
    for (int tt = 0; tt < 6; ++tt) {
      int tile = tbase + tt;
      half8 B0 = pW[tile * 64 + lane];
      half8 B1 = pW[(12 + tile) * 64 + lane];
      f32x4 C = {0.f, 0.f, 0.f, 0.f};
      C = __builtin_amdgcn_mfma_f32_16x16x32_f16(A0, B0, C, 0, 0, 0);
      C = __builtin_amdgcn_mfma_f32_16x16x32_f16(A1, B1, C, 0, 0, 0);
      int col = tile * 16 + (lane & 15);
      int rb = (lane >> 4) << 2;
      #pragma unroll
      for (int r = 0; r < 4; ++r) sg_[(rb + r) * 208 + col] = C[r];
    }
  }
  __syncthreads();

  // C: GRU update
  #pragma unroll
  for (int rep = 0; rep < 4; ++rep) {
    int idx = rep * 256 + t, j = idx >> 6, d = idx & 63;
    float rr = sigmf(sgi[j * 208 + d] + bih[d] + sgh[j * 208 + d] + bhh[d]);
    float zz = sigmf(sgi[j * 208 + 64 + d] + bih[64 + d] + sgh[j * 208 + 64 + d] + bhh[64 + d]);
    float nn = tanhf(sgi[j * 208 + 128 + d] + bih[128 + d]
                     + rr * (sgh[j * 208 + 128 + d] + bhh[128 + d]));
    float hv = (1.f - zz) * nn + zz * sh32[j * 64 + d];
    h[(size_t)(n0 + j) * 64 + d] = hv;
    sh16[j * 72 + d] = (_Float16)hv;
  }
  __syncthreads();

  // D: next-step P2/R via MFMA (cols 0-63: e2b -> P2, 64-127: rootW -> R)
  if (doPR) {
    const int abase = (lane & 15) * 72 + ((lane >> 4) << 3);
    half8 A0 = *(const half8*)(sh16 + abase);
    half8 A1 = *(const half8*)(sh16 + abase + 32);
    #pragma unroll
    for (int tt = 0; tt < 2; ++tt) {
      int tile = w * 2 + tt;
      half8 B0 = pE2R[tile * 64 + lane];
      half8 B1 = pE2R[(8 + tile) * 64 + lane];
      f32x4 C = {0.f, 0.f, 0.f, 0.f};
      C = __builtin_amdgcn_mfma_f32_16x16x32_f16(A0, B0, C, 0, 0, 0);
      C = __builtin_amdgcn_mfma_f32_16x16x32_f16(A1, B1, C, 0, 0, 0);
      int c0 = tile * 16 + (lane & 15);
      int rb = (lane >> 4) << 2;
      #pragma unroll
      for (int r = 0; r < 4; ++r) {
        int n = n0 + rb + r;
        if (c0 < 64) P2[(size_t)n * 64 + c0] = C[r];
        else R[(size_t)n * 64 + (c0 - 64)] = C[r] + rootb[c0 - 64];
      }
    }
  }
}

// ---------------- Set2Set (R4 design — unchanged) ----------------

#define SCAP 224

__global__ __launch_bounds__(256) void k_s2s(const float* __restrict__ xo,
    const int* __restrict__ gs,
    const float* __restrict__ Wih, const float* __restrict__ Whh,
    const float* __restrict__ bih, const float* __restrict__ bhh,
    float* __restrict__ qs_g) {
  __shared__ float sxo[SCAP * 65];
  __shared__ float sqs[128], shl[64], scl[64], sg[256];
  __shared__ float se[512];
  __shared__ float redm[4], ash[4], rsh[4][64];
  const int t = threadIdx.x;
  const int lane = t & 63, w = t >> 6;
  const int b = blockIdx.x;
  const int s0 = gs[b], cnt = gs[b + 1] - s0;
  const int cc = (cnt < SCAP) ? cnt : SCAP;

  for (int i = w; i < cc; i += 4) sxo[i * 65 + lane] = xo[(size_t)(s0 + i) * 64 + lane];
  if (t < 128) sqs[t] = 0.f;
  if (t < 64) { shl[t] = 0.f; scl[t] = 0.f; }
  __syncthreads();

  for (int it = 0; it < 5; ++it) {
    float a = bih[t] + bhh[t];
    #pragma unroll 8
    for (int k = 0; k < 128; ++k) a += sqs[k] * Wih[k * 256 + t];
    #pragma unroll 8
    for (int k = 0; k < 64; ++k)  a += shl[k] * Whh[k * 256 + t];
    sg[t] = a;
    __syncthreads();
    if (t < 64) {
      float i_ = sg[t], f_ = sg[64 + t], g_ = sg[128 + t], o_ = sg[192 + t];
      float cl = sigmf(f_) * scl[t] + sigmf(i_) * tanhf(g_);
      scl[t] = cl;
      shl[t] = sigmf(o_) * tanhf(cl);
    }
    __syncthreads();
    for (int i = t; i < cnt; i += 256) {
      float acc = 0.f;
      if (i < SCAP) {
        #pragma unroll 8
        for (int d = 0; d < 64; ++d) acc += sxo[i * 65 + d] * shl[d];
      } else {
        const float* xr = xo + (size_t)(s0 + i) * 64;
        #pragma unroll 8
        for (int d = 0; d < 64; ++d) acc += xr[d] * shl[d];
      }
      se[i] = acc;
    }
    __syncthreads();
    float mx = -INFINITY;
    for (int i = t; i < cnt; i += 256) mx = fmaxf(mx, se[i]);
    #pragma unroll
    for (int off = 32; off; off >>= 1) mx = fmaxf(mx, __shfl_xor(mx, off));
    if (lane == 0) redm[w] = mx;
    __syncthreads();
    const float gmax = fmaxf(fmaxf(redm[0], redm[1]), fmaxf(redm[2], redm[3]));
    float s = 0.f;
    for (int i = t; i < cnt; i += 256) {
      float aa = expf(se[i] - gmax);
      se[i] = aa;
      s += aa;
    }
    #pragma unroll
    for (int off = 32; off; off >>= 1) s += __shfl_xor(s, off);
    if (lane == 0) ash[w] = s;
    __syncthreads();
    const float gsum = ash[0] + ash[1] + ash[2] + ash[3];
    float racc = 0.f;
    for (int i = w; i < cnt; i += 4) {
      float aa = se[i];
      racc += (i < SCAP) ? aa * sxo[i * 65 + lane]
                         : aa * xo[(size_t)(s0 + i) * 64 + lane];
    }
    rsh[w][lane] = racc;
    __syncthreads();
    if (t < 64) {
      float rt_ = rsh[0][t] + rsh[1][t] + rsh[2][t] + rsh[3][t];
      sqs[t] = shl[t];
      sqs[64 + t] = rt_ / (gsum + 1e-16f);
    }
    __syncthreads();
  }
  if (t < 128) qs_g[b * 128 + t] = sqs[t];
}

// ---------------- head (R4 design — unchanged) ----------------

__global__ __launch_bounds__(256) void k_fc(const float* __restrict__ in,
    const float* __restrict__ W, const float* __restrict__ bias,
    const float* __restrict__ g, const float* __restrict__ bt,
    float* __restrict__ out, int K, int NC) {
  __shared__ float sin_[64 * 257];
  const int t = threadIdx.x, lane = t & 63, w = t >> 6;
  const int c = blockIdx.x * 4 + w;
  const int Kp = K + 1;
  for (int idx = t; idx < 64 * K; idx += 256) sin_[(idx / K) * Kp + (idx % K)] = in[idx];
  __syncthreads();
  float acc = 0.f;
  const float* wc = W + c;
  #pragma unroll 8
  for (int k = 0; k < K; ++k) acc += sin_[lane * Kp + k] * wc[(size_t)k * NC];
  acc += bias[c];
  float s = acc, s2 = acc * acc;
  #pragma unroll
  for (int off = 32; off; off >>= 1) { s += __shfl_xor(s, off); s2 += __shfl_xor(s2, off); }
  float mu = s * (1.f / 64.f);
  float rs = rsqrtf(s2 * (1.f / 64.f) - mu * mu + 1e-5f);
  out[(size_t)lane * NC + c] = fmaxf(0.f, (acc - mu) * rs * g[c] + bt[c]);
}

__global__ __launch_bounds__(256) void k_f3fo(const float* __restrict__ y2,
    const float* __restrict__ f3W, const float* __restrict__ f3b,
    const float* __restrict__ f3g, const float* __restrict__ f3bt,
    const float* __restrict__ foW, const float* __restrict__ fob,
    float* __restrict__ out) {
  __shared__ float sin_[64 * 129];
  __shared__ float sy3[64 * 33];
  const int t = threadIdx.x, lane = t & 63, w = t >> 6;
  for (int idx = t; idx < 64 * 128; idx += 256) sin_[(idx >> 7) * 129 + (idx & 127)] = y2[idx];
  __syncthreads();
  #pragma unroll
  for (int cg = 0; cg < 8; ++cg) {
    int c = w * 8 + cg;
    float acc = 0.f;
    #pragma unroll 8
    for (int k = 0; k < 128; ++k) acc += sin_[lane * 129 + k] * f3W[k * 32 + c];
    acc += f3b[c];
    float s = acc, s2 = acc * acc;
    #pragma unroll
    for (int off = 32; off; off >>= 1) { s += __shfl_xor(s, off); s2 += __shfl_xor(s2, off); }
    float mu = s * (1.f / 64.f);
    float rs = rsqrtf(s2 * (1.f / 64.f) - mu * mu + 1e-5f);
    sy3[lane * 33 + c] = fmaxf(0.f, (acc - mu) * rs * f3g[c] + f3bt[c]);
  }
  __syncthreads();
  if (t < 64) {
    float v = fob[0];
    #pragma unroll
    for (int k = 0; k < 32; ++k) v += sy3[t * 33 + k] * foW[k];
    out[t] = v;
  }
}

// ---------------- host ----------------

extern "C" void kernel_launch(void* const* d_in, const int* in_sizes, int n_in,
                              void* d_out, int out_size, void* d_ws, size_t ws_size,
                              hipStream_t stream) {
  (void)in_sizes; (void)n_in; (void)out_size; (void)ws_size;
  const float* x      = (const float*)d_in[0];
  const float* eattr  = (const float*)d_in[1];
  const int*   ei     = (const int*)d_in[2];
  const int*   batch  = (const int*)d_in[3];
  const float* lin0_W = (const float*)d_in[4];
  const float* lin0_b = (const float*)d_in[5];
  const float* bn0_g  = (const float*)d_in[6];
  const float* bn0_b  = (const float*)d_in[7];
  const float* e1_W   = (const float*)d_in[8];
  const float* e1_b   = (const float*)d_in[9];
  const float* ebn_g  = (const float*)d_in[10];
  const float* ebn_b  = (const float*)d_in[11];
  const float* e2_W   = (const float*)d_in[12];
  const float* e2_b   = (const float*)d_in[13];
  const float* root_W = (const float*)d_in[14];
  const float* root_b = (const float*)d_in[15];
  const float* gWih   = (const float*)d_in[16];
  const float* gWhh   = (const float*)d_in[17];
  const float* gbih   = (const float*)d_in[18];
  const float* gbhh   = (const float*)d_in[19];
  const float* lWih   = (const float*)d_in[20];
  const float* lWhh   = (const float*)d_in[21];
  const float* lbih   = (const float*)d_in[22];
  const float* lbhh   = (const float*)d_in[23];
  const float* f1_W   = (const float*)d_in[24];
  const float* f1_b   = (const float*)d_in[25];
  const float* f1_g   = (const float*)d_in[26];
  const float* f1_bt  = (const float*)d_in[27];
  const float* f2_W   = (const float*)d_in[28];
  const float* f2_b   = (const float*)d_in[29];
  const float* f2_g   = (const float*)d_in[30];
  const float* f2_bt  = (const float*)d_in[31];
  const float* f3_W   = (const float*)d_in[32];
  const float* f3_b   = (const float*)d_in[33];
  const float* f3_g   = (const float*)d_in[34];
  const float* f3_bt  = (const float*)d_in[35];
  const float* fo_W   = (const float*)d_in[36];
  const float* fo_b   = (const float*)d_in[37];
  const int* srcI = ei;
  const int* dstI = ei + E_;

  char* base = (char*)d_ws;
  size_t off = 0;
  auto alloc = [&](size_t bytes) -> void* {
    off = (off + 255) & ~(size_t)255;
    void* p = base + off;
    off += bytes;
    return p;
  };
  float* t0    = (float*)alloc((size_t)N_ * 64 * 4);
  float* t1    = (float*)alloc((size_t)E_ * 128 * 4);
  float* x0    = (float*)alloc((size_t)N_ * 64 * 4);
  float* hb    = (float*)alloc((size_t)N_ * 64 * 4);
  _Float16* ehq = (_Float16*)alloc((size_t)E_ * 128 * 2);
  half8* w2p8  = (half8*)alloc((size_t)65536 * 16);
  half8* pWih  = (half8*)alloc((size_t)1536 * 16);
  half8* pWhh  = (half8*)alloc((size_t)1536 * 16);
  half8* pE2R  = (half8*)alloc((size_t)1024 * 16);
  float* P2    = (float*)alloc((size_t)N_ * 64 * 4);
  float* R     = (float*)alloc((size_t)N_ * 64 * 4);
  float* msg   = (float*)alloc((size_t)E_ * 64 * 4);
  int* cnt_i   = (int*)alloc((size_t)N_ * 4);
  int* cursor  = (int*)alloc((size_t)N_ * 4);
  int* row_start = (int*)alloc((size_t)(N_ + 1) * 4);
  int* csr     = (int*)alloc((size_t)E_ * 4);
  float* cntf  = (float*)alloc((size_t)N_ * 4);
  int* nodecnt = (int*)alloc(64 * 4);
  int* gs      = (int*)alloc(65 * 4);
  float* mean0 = (float*)alloc(64 * 4);
  float* rstd0 = (float*)alloc(64 * 4);
  float* meanE = (float*)alloc(128 * 4);
  float* rstdE = (float*)alloc(128 * 4);
  float* qs    = (float*)alloc((size_t)B_ * 128 * 4);
  float* y1    = (float*)alloc((size_t)B_ * 256 * 4);
  float* y2    = (float*)alloc((size_t)B_ * 128 * 4);

  hipMemsetAsync(cnt_i, 0, (size_t)N_ * 4, stream);
  hipMemsetAsync(nodecnt, 0, 64 * 4, stream);

  k_pre1<<<18592, 256, 0, stream>>>(x, lin0_W, lin0_b, eattr, e1_W, e1_b,
                                    dstI, batch, t0, t1, cnt_i, nodecnt);
  k_stats<<<192, 256, 0, stream>>>(t0, t1, mean0, rstd0, meanE, rstdE);
  k_pre3<<<18704, 256, 0, stream>>>(t0, mean0, rstd0, bn0_g, bn0_b, x0, hb,
                                    t1, meanE, rstdE, ebn_g, ebn_b, ehq, e2_W, w2p8,
                                    gWih, gWhh, pWih, pWhh, e2_b, root_W, pE2R);
  k_scans<<<1, 1024, 0, stream>>>(cnt_i, nodecnt, row_start, cursor, cntf, gs);
  k_fillnl<<<2176, 256, 0, stream>>>(dstI, cursor, csr, x0, e2_b, root_W, root_b, P2, R);

  for (int s = 0; s < 4; ++s) {
    k_msg<<<E_ / 64, 256, 0, stream>>>(ehq, w2p8, (s == 0) ? x0 : hb, P2, srcI, msg);
    k_node<<<N_ / 16, 256, 0, stream>>>(msg, csr, row_start, cntf,
                                        pWih, pWhh, gbih, gbhh, pE2R, root_b,
                                        hb, P2, R, (s < 3) ? 1 : 0);
  }

  k_s2s<<<B_, 256, 0, stream>>>(hb, gs, lWih, lWhh, lbih, lbhh, qs);
  k_fc<<<64, 256, 0, stream>>>(qs, f1_W, f1_b, f1_g, f1_bt, y1, 128, 256);
  k_fc<<<32, 256, 0, stream>>>(y1, f2_W, f2_b, f2_g, f2_bt, y2, 256, 128);
  k_f3fo<<<1, 256, 0, stream>>>(y2, f3_W, f3_b, f3_g, f3_bt, fo_W, fo_b, (float*)d_out);
}

// Round 11
// 621.974 us; speedup vs baseline: 1.6544x; 1.0744x over previous
//
#include <hip/hip_runtime.h>
#include <hip/hip_bf16.h>

// GraphNet (NNConv/GRU/Set2Set) forward, MI355X.
// R6b: pre-pipeline vectorized (f32x4 IO, 4-8 outputs/thread), k_stats ->
// coalesced partial-sums + finalize folded into k_scans. msg/node unchanged (R5).
// Fix vs R6: k_statsP t0 branch iteration count (was 4x OOB).

#define N_  8192
#define E_  32768
#define B_  64
#define D_  64
#define FN_ 32
#define FE_ 16
#define EH_ 128

typedef _Float16 half8 __attribute__((ext_vector_type(8)));
typedef float    f32x4 __attribute__((ext_vector_type(4)));

__device__ __forceinline__ float sigmf(float x) { return 1.f / (1.f + expf(-x)); }

#if __has_builtin(__builtin_amdgcn_global_load_lds)
#define HAVE_GLDS 1
__device__ __forceinline__ void gl2lds16(const void* g, void* l) {
  __builtin_amdgcn_global_load_lds(
      (const __attribute__((address_space(1))) void*)g,
      (__attribute__((address_space(3))) void*)l, 16, 0, 0);
}
#else
#define HAVE_GLDS 0
#endif

// ---------------- P1: lin0 + e1 (vectorized) + degree/graph counting ----------------

__global__ __launch_bounds__(256) void k_pre1(const float* __restrict__ x,
    const float* __restrict__ lin0W, const float* __restrict__ lin0b,
    const float* __restrict__ ea, const float* __restrict__ e1W, const float* __restrict__ e1b,
    const int* __restrict__ dstI, const int* __restrict__ batch,
    float* __restrict__ t0, float* __restrict__ t1,
    int* __restrict__ cnt_i, int* __restrict__ nodecnt) {
  const int bid = blockIdx.x, t = threadIdx.x;
  if (bid < 512) {                                     // lin0: N*16 threads, 4 out/thread
    int gid = bid * 256 + t;
    int n = gid >> 4, d4 = (gid & 15) * 4;
    const float* xr = x + (size_t)n * FN_;
    f32x4 a = *(const f32x4*)&lin0b[d4];
    #pragma unroll
    for (int i = 0; i < FN_; ++i)
      a += xr[i] * *(const f32x4*)&lin0W[i * 64 + d4];
    *(f32x4*)&t0[(size_t)n * 64 + d4] = a;
  } else if (bid < 2560) {                             // e1: E*16 threads, 8 out/thread
    int gid = (bid - 512) * 256 + t;
    int n = gid >> 4, j8 = (gid & 15) * 8;
    const float* er = ea + (size_t)n * FE_;
    f32x4 a0 = *(const f32x4*)&e1b[j8];
    f32x4 a1 = *(const f32x4*)&e1b[j8 + 4];
    #pragma unroll
    for (int i = 0; i < FE_; ++i) {
      float ev = er[i];
      a0 += ev * *(const f32x4*)&e1W[i * 128 + j8];
      a1 += ev * *(const f32x4*)&e1W[i * 128 + j8 + 4];
    }
    *(f32x4*)&t1[(size_t)n * 128 + j8] = a0;
    *(f32x4*)&t1[(size_t)n * 128 + j8 + 4] = a1;
  } else if (bid < 2688) {                             // edge degree count
    atomicAdd(&cnt_i[dstI[(bid - 2560) * 256 + t]], 1);
  } else {                                             // graph node count
    atomicAdd(&nodecnt[batch[(bid - 2688) * 256 + t]], 1);
  }
}

// ---------------- P2: BN stats partial sums (coalesced f32x4 scans) ----------------

__global__ __launch_bounds__(256) void k_statsP(const float* __restrict__ t0,
    const float* __restrict__ t1, float* __restrict__ pT, float* __restrict__ pE) {
  __shared__ float red[256][8];
  const int bid = blockIdx.x, t = threadIdx.x;
  if (bid < 16) {                                      // t0: 131072 f32x4, colgroup t&15
    const f32x4* v = (const f32x4*)t0;
    f32x4 s = {0.f,0.f,0.f,0.f}, s2 = {0.f,0.f,0.f,0.f};
    #pragma unroll 8
    for (int it = 0; it < 32; ++it) {                  // 16 blk x 32 it x 256 thr = 131072
      f32x4 xv = v[bid * 8192 + it * 256 + t];
      s += xv; s2 += xv * xv;
    }
    #pragma unroll
    for (int j = 0; j < 4; ++j) { red[t][j] = s[j]; red[t][4 + j] = s2[j]; }
    __syncthreads();
    if (t < 64) {
      int g = t >> 2, comp = t & 3;
      float a = 0.f, b = 0.f;
      #pragma unroll
      for (int k = 0; k < 16; ++k) { a += red[g + k * 16][comp]; b += red[g + k * 16][4 + comp]; }
      pT[bid * 128 + t] = a;
      pT[bid * 128 + 64 + t] = b;
    }
  } else {                                             // t1: 1048576 f32x4, colgroup t&31
    int eb = bid - 16;
    const f32x4* v = (const f32x4*)t1;
    f32x4 s = {0.f,0.f,0.f,0.f}, s2 = {0.f,0.f,0.f,0.f};
    #pragma unroll
    for (int it = 0; it < 16; ++it) {                  // 256 blk x 16 it x 256 thr = 1048576
      f32x4 xv = v[eb * 4096 + it * 256 + t];
      s += xv; s2 += xv * xv;
    }
    #pragma unroll
    for (int j = 0; j < 4; ++j) { red[t][j] = s[j]; red[t][4 + j] = s2[j]; }
    __syncthreads();
    if (t < 128) {
      int g = t >> 2, comp = t & 3;
      float a = 0.f, b = 0.f;
      #pragma unroll
      for (int k = 0; k < 8; ++k) { a += red[g + k * 32][comp]; b += red[g + k * 32][4 + comp]; }
      pE[eb * 256 + t] = a;
      pE[eb * 256 + 128 + t] = b;
    }
  }
}

// ---------------- CSR scan + stats finalize ----------------

__global__ __launch_bounds__(1024) void k_scans(const int* __restrict__ cnt,
    const int* __restrict__ nodecnt, int* __restrict__ row_start,
    int* __restrict__ cursor, float* __restrict__ cntf, int* __restrict__ gs,
    const float* __restrict__ pT, const float* __restrict__ pE,
    float* __restrict__ mean0, float* __restrict__ rstd0,
    float* __restrict__ meanE, float* __restrict__ rstdE) {
  __shared__ int sp[1024];
  int t = threadIdx.x;
  // --- stats finalize: E cols (128 x 8 thr), N cols (64 x 8 thr) ---
  {
    int c = t >> 3, k0 = t & 7;
    float s = 0.f, q = 0.f;
    for (int b = k0; b < 256; b += 8) { s += pE[b * 256 + c]; q += pE[b * 256 + 128 + c]; }
    s += __shfl_xor(s, 1); s += __shfl_xor(s, 2); s += __shfl_xor(s, 4);
    q += __shfl_xor(q, 1); q += __shfl_xor(q, 2); q += __shfl_xor(q, 4);
    if (k0 == 0) {
      float mu = s / (float)E_;
      meanE[c] = mu;
      rstdE[c] = rsqrtf(q / (float)E_ - mu * mu + 1e-5f);
    }
    if (t < 512) {
      int c2 = t >> 3, k2 = t & 7;
      float s3 = pT[k2 * 128 + c2] + pT[(k2 + 8) * 128 + c2];
      float q3 = pT[k2 * 128 + 64 + c2] + pT[(k2 + 8) * 128 + 64 + c2];
      s3 += __shfl_xor(s3, 1); s3 += __shfl_xor(s3, 2); s3 += __shfl_xor(s3, 4);
      q3 += __shfl_xor(q3, 1); q3 += __shfl_xor(q3, 2); q3 += __shfl_xor(q3, 4);
      if (k2 == 0) {
        float mu = s3 / (float)N_;
        mean0[c2] = mu;
        rstd0[c2] = rsqrtf(q3 / (float)N_ - mu * mu + 1e-5f);
      }
    }
  }
  // --- graph offsets + CSR scan ---
  if (t == 0) {
    int a = 0;
    for (int b = 0; b < B_; ++b) { gs[b] = a; a += nodecnt[b]; }
    gs[B_] = a;
  }
  int v[8]; int s = 0;
  #pragma unroll
  for (int j = 0; j < 8; ++j) { v[j] = cnt[t * 8 + j]; s += v[j]; }
  sp[t] = s;
  __syncthreads();
  for (int off = 1; off < 1024; off <<= 1) {
    int a = (t >= off) ? sp[t - off] : 0;
    __syncthreads();
    sp[t] += a;
    __syncthreads();
  }
  int run = sp[t] - s;
  #pragma unroll
  for (int j = 0; j < 8; ++j) {
    row_start[t * 8 + j] = run;
    cursor[t * 8 + j] = run;
    cntf[t * 8 + j] = fmaxf(1.0f, (float)v[j]);
    run += v[j];
  }
  if (t == 1023) row_start[N_] = run;
}

// ---------------- P3: bnrelu0 + bnrelu_eh (vectorized) + weight packing ----------------

__global__ __launch_bounds__(256) void k_pre3(const float* __restrict__ t0,
    const float* __restrict__ mean0, const float* __restrict__ rstd0,
    const float* __restrict__ bn0g, const float* __restrict__ bn0b,
    float* __restrict__ x0, float* __restrict__ hb,
    const float* __restrict__ t1, const float* __restrict__ meanE,
    const float* __restrict__ rstdE, const float* __restrict__ ebng,
    const float* __restrict__ ebnb, _Float16* __restrict__ ehq,
    const float* __restrict__ e2W, half8* __restrict__ w2p8,
    const float* __restrict__ gWih, const float* __restrict__ gWhh,
    half8* __restrict__ pWih, half8* __restrict__ pWhh,
    const float* __restrict__ e2b, const float* __restrict__ rootW,
    half8* __restrict__ pE2R) {
  const int bid = blockIdx.x, t = threadIdx.x;
  if (bid < 512) {                                     // bnrelu0: 4/thread
    int gid = bid * 256 + t;
    int n = gid >> 4, d4 = (gid & 15) * 4;
    f32x4 v  = *(const f32x4*)&t0[(size_t)n * 64 + d4];
    f32x4 mu = *(const f32x4*)&mean0[d4];
    f32x4 rs = *(const f32x4*)&rstd0[d4];
    f32x4 gg = *(const f32x4*)&bn0g[d4];
    f32x4 bb = *(const f32x4*)&bn0b[d4];
    f32x4 r = (v - mu) * rs * gg + bb;
    #pragma unroll
    for (int j = 0; j < 4; ++j) r[j] = fmaxf(0.f, r[j]);
    *(f32x4*)&x0[(size_t)n * 64 + d4] = r;
    *(f32x4*)&hb[(size_t)n * 64 + d4] = r;
  } else if (bid < 2560) {                             // bnrelu_eh: 8/thread, half8 store
    int gid = (bid - 512) * 256 + t;
    int n = gid >> 4, j8 = (gid & 15) * 8;
    half8 o;
    #pragma unroll
    for (int hc = 0; hc < 2; ++hc) {
      f32x4 v  = *(const f32x4*)&t1[(size_t)n * 128 + j8 + hc * 4];
      f32x4 mu = *(const f32x4*)&meanE[j8 + hc * 4];
      f32x4 rs = *(const f32x4*)&rstdE[j8 + hc * 4];
      f32x4 gg = *(const f32x4*)&ebng[j8 + hc * 4];
      f32x4 bb = *(const f32x4*)&ebnb[j8 + hc * 4];
      f32x4 r = (v - mu) * rs * gg + bb;
      #pragma unroll
      for (int j = 0; j < 4; ++j) o[hc * 4 + j] = (_Float16)fmaxf(0.f, r[j]);
    }
    *(half8*)&ehq[(size_t)n * 128 + j8] = o;
  } else if (bid < 2816) {                             // w2pack: 65536 items
    int tt = (bid - 2560) * 256 + t;
    int l = tt & 63, nf = (tt >> 6) & 3, kf = (tt >> 8) & 3, i = tt >> 10;
    half8 v;
    #pragma unroll
    for (int j = 0; j < 8; ++j) {
      int k = kf * 32 + ((l >> 4) << 3) + j;
      v[j] = (_Float16)e2W[(size_t)k * 4096 + i * 64 + (nf << 4) + (l & 15)];
    }
    w2p8[tt] = v;
  } else if (bid < 2828) {                             // pack gWih/gWhh: 3072 items
    int tt2 = (bid - 2816) * 256 + t;
    int tab = (tt2 >= 1536);
    int rr = tab ? tt2 - 1536 : tt2;
    int lane = rr & 63, q = rr >> 6;
    int tile = q % 12, kf = q / 12;
    const float* W = tab ? gWhh : gWih;
    int col = tile * 16 + (lane & 15);
    half8 v;
    #pragma unroll
    for (int j = 0; j < 8; ++j) {
      int k = kf * 32 + ((lane >> 4) << 3) + j;
      v[j] = (_Float16)W[k * 192 + col];
    }
    (tab ? pWhh : pWih)[rr] = v;
  } else {                                             // pack e2b|rootW: 1024 items
    int rr = (bid - 2828) * 256 + t;
    int lane = rr & 63, q = rr >> 6;
    int tile = q % 8, kf = q / 8;
    int col = tile * 16 + (lane & 15);
    half8 v;
    #pragma unroll
    for (int j = 0; j < 8; ++j) {
      int k = kf * 32 + ((lane >> 4) << 3) + j;
      v[j] = (_Float16)((col < 64) ? e2b[k * 64 + col] : rootW[k * 64 + (col - 64)]);
    }
    pE2R[rr] = v;
  }
}

// ---------------- CSR fill + step-0 P2/R ----------------

__global__ __launch_bounds__(256) void k_fillnl(const int* __restrict__ dstI,
    int* __restrict__ cursor, int* __restrict__ csr,
    const float* __restrict__ x0, const float* __restrict__ e2b,
    const float* __restrict__ rootW, const float* __restrict__ rootb,
    float* __restrict__ P2, float* __restrict__ R) {
  const int bid = blockIdx.x, t = threadIdx.x;
  if (bid < 128) {                                     // csr fill
    int e = bid * 256 + t;
    int pos = atomicAdd(&cursor[dstI[e]], 1);
    csr[pos] = e;
  } else {                                             // step-0 P2/R (f32)
    int gid = (bid - 128) * 256 + t;
    int n = gid >> 6, d = gid & 63;
    const float* xr = x0 + (size_t)n * 64;
    float ap = 0.f, ar = rootb[d];
    #pragma unroll 8
    for (int i = 0; i < 64; ++i) {
      float xv = xr[i];
      ap += xv * e2b[i * 64 + d];
      ar += xv * rootW[i * 64 + d];
    }
    P2[gid] = ap; R[gid] = ar;
  }
}

// ---------------- fused message GEMM (R5, unchanged) ----------------

__global__ __launch_bounds__(256) void k_msg(const _Float16* __restrict__ ehq,
    const half8* __restrict__ w2p8, const float* __restrict__ xo, const float* __restrict__ P2,
    const int* __restrict__ srcI, float* __restrict__ msg) {
  __shared__ half8 bbuf[2][1024];
  __shared__ float xs[64][65];
  __shared__ int ssrc[64];
  const int tid = threadIdx.x;
  const int lane = tid & 63;
  const int w = tid >> 6;
  const int be = blockIdx.x * 64;

  if (tid < 64) ssrc[tid] = srcI[be + tid];
#if HAVE_GLDS
  #pragma unroll
  for (int c = 0; c < 4; ++c) gl2lds16(w2p8 + c * 256 + tid, &bbuf[0][c * 256 + tid]);
#endif
  __syncthreads();
  for (int r = w; r < 64; r += 4) xs[r][lane] = xo[(size_t)ssrc[r] * 64 + lane];

  half8 A[4][4];
  #pragma unroll
  for (int rt = 0; rt < 4; ++rt) {
    const _Float16* ap = ehq + (size_t)(be + rt * 16 + (lane & 15)) * 128 + ((lane >> 4) << 3);
    #pragma unroll
    for (int kf = 0; kf < 4; ++kf) A[rt][kf] = *(const half8*)(ap + kf * 32);
  }
#if !HAVE_GLDS
  #pragma unroll
  for (int c = 0; c < 4; ++c) bbuf[0][c * 256 + tid] = w2p8[c * 256 + tid];
#endif

  f32x4 acc[4] = {{0.f,0.f,0.f,0.f},{0.f,0.f,0.f,0.f},{0.f,0.f,0.f,0.f},{0.f,0.f,0.f,0.f}};
  __syncthreads();

  for (int i = 0; i < 64; ++i) {
    const int inext = (i < 63) ? i + 1 : 63;
    const half8* gp = w2p8 + (size_t)inext * 1024;
#if HAVE_GLDS
    half8* nb = &bbuf[(i + 1) & 1][0];
    #pragma unroll
    for (int c = 0; c < 4; ++c) gl2lds16(gp + c * 256 + tid, nb + c * 256 + tid);
#else
    half8 p[4];
    #pragma unroll
    for (int c = 0; c < 4; ++c) p[c] = gp[c * 256 + tid];
#endif

    const half8* bb = bbuf[i & 1];
    half8 Bf[4];
    #pragma unroll
    for (int kf = 0; kf < 4; ++kf) Bf[kf] = bb[(kf * 4 + w) * 64 + lane];

    #pragma unroll
    for (int rt = 0; rt < 4; ++rt) {
      f32x4 C = {0.f, 0.f, 0.f, 0.f};
      #pragma unroll
      for (int kf = 0; kf < 4; ++kf)
        C = __builtin_amdgcn_mfma_f32_16x16x32_f16(A[rt][kf], Bf[kf], C, 0, 0, 0);
      const int rbase = rt * 16 + ((lane >> 4) << 2);
      #pragma unroll
      for (int r = 0; r < 4; ++r) acc[rt][r] += xs[rbase + r][i] * C[r];
    }
#if !HAVE_GLDS
    half8* nb = &bbuf[(i + 1) & 1][0];
    #pragma unroll
    for (int c = 0; c < 4; ++c) nb[c * 256 + tid] = p[c];
#endif
    __syncthreads();
  }

  const int col = (w << 4) + (lane & 15);
  #pragma unroll
  for (int rt = 0; rt < 4; ++rt) {
    const int rbase = rt * 16 + ((lane >> 4) << 2);
    #pragma unroll
    for (int r = 0; r < 4; ++r) {
      const int row = rbase + r;
      const int e = be + row;
      const int sn = ssrc[row];
      msg[(size_t)e * 64 + col] = acc[rt][r] + P2[(size_t)sn * 64 + col];
    }
  }
}

// ---------------- fused node update (R5, unchanged) ----------------

__global__ __launch_bounds__(256) void k_node(const float* __restrict__ msg,
    const int* __restrict__ csr, const int* __restrict__ row_start,
    const float* __restrict__ cntf,
    const half8* __restrict__ pWih, const half8* __restrict__ pWhh,
    const float* __restrict__ bih, const float* __restrict__ bhh,
    const half8* __restrict__ pE2R, const float* __restrict__ rootb,
    float* __restrict__ h, float* __restrict__ P2, float* __restrict__ R, int doPR) {
  __shared__ _Float16 sm16[16 * 72];
  __shared__ _Float16 sh16[16 * 72];
  __shared__ float sh32[16 * 64];
  __shared__ float sgi[16 * 208];
  __shared__ float sgh[16 * 208];
  const int t = threadIdx.x, lane = t & 63, w = t >> 6;
  const int n0 = blockIdx.x * 16;

  #pragma unroll
  for (int g = 0; g < 4; ++g) {
    int nl = g * 4 + w, n = n0 + nl;
    int e0 = row_start[n], e1 = row_start[n + 1];
    float acc = 0.f;
    for (int idx = e0; idx < e1; ++idx) acc += msg[(size_t)csr[idx] * 64 + lane];
    float mval = fmaxf(0.f, acc / cntf[n] + R[(size_t)n * 64 + lane]);
    float hval = h[(size_t)n * 64 + lane];
    sm16[nl * 72 + lane] = (_Float16)mval;
    sh16[nl * 72 + lane] = (_Float16)hval;
    sh32[nl * 64 + lane] = hval;
  }
  __syncthreads();

  {
    const _Float16* As = (w < 2) ? sm16 : sh16;
    const half8* pW = (w < 2) ? pWih : pWhh;
    float* sg_ = (w < 2) ? sgi : sgh;
    const int abase = (lane & 15) * 72 + ((lane >> 4) << 3);
    half8 A0 = *(const half8*)(As + abase);
    half8 A1 = *(const half8*)(As + abase + 32);
    const int tbase = (w & 1) * 6;
    #pragma unroll
    for (int tt = 0; tt < 6; ++tt) {
      int tile = tbase + tt;
      half8 B0 = pW[tile * 64 + lane];
      half8 B1 = pW[(12 + tile) * 64 + lane];
      f32x4 C = {0.f, 0.f, 0.f, 0.f};
      C = __builtin_amdgcn_mfma_f32_16x16x32_f16(A0, B0, C, 0, 0, 0);
      C = __builtin_amdgcn_mfma_f32_16x16x32_f16(A1, B1, C, 0, 0, 0);
      int col = tile * 16 + (lane & 15);
      int rb = (lane >> 4) << 2;
      #pragma unroll
      for (int r = 0; r < 4; ++r) sg_[(rb + r) * 208 + col] = C[r];
    }
  }
  __syncthreads();

  #pragma unroll
  for (int rep = 0; rep < 4; ++rep) {
    int idx = rep * 256 + t, j = idx >> 6, d = idx & 63;
    float rr = sigmf(sgi[j * 208 + d] + bih[d] + sgh[j * 208 + d] + bhh[d]);
    float zz = sigmf(sgi[j * 208 + 64 + d] + bih[64 + d] + sgh[j * 208 + 64 + d] + bhh[64 + d]);
    float nn = tanhf(sgi[j * 208 + 128 + d] + bih[128 + d]
                     + rr * (sgh[j * 208 + 128 + d] + bhh[128 + d]));
    float hv = (1.f - zz) * nn + zz * sh32[j * 64 + d];
    h[(size_t)(n0 + j) * 64 + d] = hv;
    sh16[j * 72 + d] = (_Float16)hv;
  }
  __syncthreads();

  if (doPR) {
    const int abase = (lane & 15) * 72 + ((lane >> 4) << 3);
    half8 A0 = *(const half8*)(sh16 + abase);
    half8 A1 = *(const half8*)(sh16 + abase + 32);
    #pragma unroll
    for (int tt = 0; tt < 2; ++tt) {
      int tile = w * 2 + tt;
      half8 B0 = pE2R[tile * 64 + lane];
      half8 B1 = pE2R[(8 + tile) * 64 + lane];
      f32x4 C = {0.f, 0.f, 0.f, 0.f};
      C = __builtin_amdgcn_mfma_f32_16x16x32_f16(A0, B0, C, 0, 0, 0);
      C = __builtin_amdgcn_mfma_f32_16x16x32_f16(A1, B1, C, 0, 0, 0);
      int c0 = tile * 16 + (lane & 15);
      int rb = (lane >> 4) << 2;
      #pragma unroll
      for (int r = 0; r < 4; ++r) {
        int n = n0 + rb + r;
        if (c0 < 64) P2[(size_t)n * 64 + c0] = C[r];
        else R[(size_t)n * 64 + (c0 - 64)] = C[r] + rootb[c0 - 64];
      }
    }
  }
}

// ---------------- Set2Set (R4 design — unchanged) ----------------

#define SCAP 224

__global__ __launch_bounds__(256) void k_s2s(const float* __restrict__ xo,
    const int* __restrict__ gs,
    const float* __restrict__ Wih, const float* __restrict__ Whh,
    const float* __restrict__ bih, const float* __restrict__ bhh,
    float* __restrict__ qs_g) {
  __shared__ float sxo[SCAP * 65];
  __shared__ float sqs[128], shl[64], scl[64], sg[256];
  __shared__ float se[512];
  __shared__ float redm[4], ash[4], rsh[4][64];
  const int t = threadIdx.x;
  const int lane = t & 63, w = t >> 6;
  const int b = blockIdx.x;
  const int s0 = gs[b], cnt = gs[b + 1] - s0;
  const int cc = (cnt < SCAP) ? cnt : SCAP;

  for (int i = w; i < cc; i += 4) sxo[i * 65 + lane] = xo[(size_t)(s0 + i) * 64 + lane];
  if (t < 128) sqs[t] = 0.f;
  if (t < 64) { shl[t] = 0.f; scl[t] = 0.f; }
  __syncthreads();

  for (int it = 0; it < 5; ++it) {
    float a = bih[t] + bhh[t];
    #pragma unroll 8
    for (int k = 0; k < 128; ++k) a += sqs[k] * Wih[k * 256 + t];
    #pragma unroll 8
    for (int k = 0; k < 64; ++k)  a += shl[k] * Whh[k * 256 + t];
    sg[t] = a;
    __syncthreads();
    if (t < 64) {
      float i_ = sg[t], f_ = sg[64 + t], g_ = sg[128 + t], o_ = sg[192 + t];
      float cl = sigmf(f_) * scl[t] + sigmf(i_) * tanhf(g_);
      scl[t] = cl;
      shl[t] = sigmf(o_) * tanhf(cl);
    }
    __syncthreads();
    for (int i = t; i < cnt; i += 256) {
      float acc = 0.f;
      if (i < SCAP) {
        #pragma unroll 8
        for (int d = 0; d < 64; ++d) acc += sxo[i * 65 + d] * shl[d];
      } else {
        const float* xr = xo + (size_t)(s0 + i) * 64;
        #pragma unroll 8
        for (int d = 0; d < 64; ++d) acc += xr[d] * shl[d];
      }
      se[i] = acc;
    }
    __syncthreads();
    float mx = -INFINITY;
    for (int i = t; i < cnt; i += 256) mx = fmaxf(mx, se[i]);
    #pragma unroll
    for (int off = 32; off; off >>= 1) mx = fmaxf(mx, __shfl_xor(mx, off));
    if (lane == 0) redm[w] = mx;
    __syncthreads();
    const float gmax = fmaxf(fmaxf(redm[0], redm[1]), fmaxf(redm[2], redm[3]));
    float s = 0.f;
    for (int i = t; i < cnt; i += 256) {
      float aa = expf(se[i] - gmax);
      se[i] = aa;
      s += aa;
    }
    #pragma unroll
    for (int off = 32; off; off >>= 1) s += __shfl_xor(s, off);
    if (lane == 0) ash[w] = s;
    __syncthreads();
    const float gsum = ash[0] + ash[1] + ash[2] + ash[3];
    float racc = 0.f;
    for (int i = w; i < cnt; i += 4) {
      float aa = se[i];
      racc += (i < SCAP) ? aa * sxo[i * 65 + lane]
                         : aa * xo[(size_t)(s0 + i) * 64 + lane];
    }
    rsh[w][lane] = racc;
    __syncthreads();
    if (t < 64) {
      float rt_ = rsh[0][t] + rsh[1][t] + rsh[2][t] + rsh[3][t];
      sqs[t] = shl[t];
      sqs[64 + t] = rt_ / (gsum + 1e-16f);
    }
    __syncthreads();
  }
  if (t < 128) qs_g[b * 128 + t] = sqs[t];
}

// ---------------- head (R4 design — unchanged) ----------------

__global__ __launch_bounds__(256) void k_fc(const float* __restrict__ in,
    const float* __restrict__ W, const float* __restrict__ bias,
    const float* __restrict__ g, const float* __restrict__ bt,
    float* __restrict__ out, int K, int NC) {
  __shared__ float sin_[64 * 257];
  const int t = threadIdx.x, lane = t & 63, w = t >> 6;
  const int c = blockIdx.x * 4 + w;
  const int Kp = K + 1;
  for (int idx = t; idx < 64 * K; idx += 256) sin_[(idx / K) * Kp + (idx % K)] = in[idx];
  __syncthreads();
  float acc = 0.f;
  const float* wc = W + c;
  #pragma unroll 8
  for (int k = 0; k < K; ++k) acc += sin_[lane * Kp + k] * wc[(size_t)k * NC];
  acc += bias[c];
  float s = acc, s2 = acc * acc;
  #pragma unroll
  for (int off = 32; off; off >>= 1) { s += __shfl_xor(s, off); s2 += __shfl_xor(s2, off); }
  float mu = s * (1.f / 64.f);
  float rs = rsqrtf(s2 * (1.f / 64.f) - mu * mu + 1e-5f);
  out[(size_t)lane * NC + c] = fmaxf(0.f, (acc - mu) * rs * g[c] + bt[c]);
}

__global__ __launch_bounds__(256) void k_f3fo(const float* __restrict__ y2,
    const float* __restrict__ f3W, const float* __restrict__ f3b,
    const float* __restrict__ f3g, const float* __restrict__ f3bt,
    const float* __restrict__ foW, const float* __restrict__ fob,
    float* __restrict__ out) {
  __shared__ float sin_[64 * 129];
  __shared__ float sy3[64 * 33];
  const int t = threadIdx.x, lane = t & 63, w = t >> 6;
  for (int idx = t; idx < 64 * 128; idx += 256) sin_[(idx >> 7) * 129 + (idx & 127)] = y2[idx];
  __syncthreads();
  #pragma unroll
  for (int cg = 0; cg < 8; ++cg) {
    int c = w * 8 + cg;
    float acc = 0.f;
    #pragma unroll 8
    for (int k = 0; k < 128; ++k) acc += sin_[lane * 129 + k] * f3W[k * 32 + c];
    acc += f3b[c];
    float s = acc, s2 = acc * acc;
    #pragma unroll
    for (int off = 32; off; off >>= 1) { s += __shfl_xor(s, off); s2 += __shfl_xor(s2, off); }
    float mu = s * (1.f / 64.f);
    float rs = rsqrtf(s2 * (1.f / 64.f) - mu * mu + 1e-5f);
    sy3[lane * 33 + c] = fmaxf(0.f, (acc - mu) * rs * f3g[c] + f3bt[c]);
  }
  __syncthreads();
  if (t < 64) {
    float v = fob[0];
    #pragma unroll
    for (int k = 0; k < 32; ++k) v += sy3[t * 33 + k] * foW[k];
    out[t] = v;
  }
}

// ---------------- host ----------------

extern "C" void kernel_launch(void* const* d_in, const int* in_sizes, int n_in,
                              void* d_out, int out_size, void* d_ws, size_t ws_size,
                              hipStream_t stream) {
  (void)in_sizes; (void)n_in; (void)out_size; (void)ws_size;
  const float* x      = (const float*)d_in[0];
  const float* eattr  = (const float*)d_in[1];
  const int*   ei     = (const int*)d_in[2];
  const int*   batch  = (const int*)d_in[3];
  const float* lin0_W = (const float*)d_in[4];
  const float* lin0_b = (const float*)d_in[5];
  const float* bn0_g  = (const float*)d_in[6];
  const float* bn0_b  = (const float*)d_in[7];
  const float* e1_W   = (const float*)d_in[8];
  const float* e1_b   = (const float*)d_in[9];
  const float* ebn_g  = (const float*)d_in[10];
  const float* ebn_b  = (const float*)d_in[11];
  const float* e2_W   = (const float*)d_in[12];
  const float* e2_b   = (const float*)d_in[13];
  const float* root_W = (const float*)d_in[14];
  const float* root_b = (const float*)d_in[15];
  const float* gWih   = (const float*)d_in[16];
  const float* gWhh   = (const float*)d_in[17];
  const float* gbih   = (const float*)d_in[18];
  const float* gbhh   = (const float*)d_in[19];
  const float* lWih   = (const float*)d_in[20];
  const float* lWhh   = (const float*)d_in[21];
  const float* lbih   = (const float*)d_in[22];
  const float* lbhh   = (const float*)d_in[23];
  const float* f1_W   = (const float*)d_in[24];
  const float* f1_b   = (const float*)d_in[25];
  const float* f1_g   = (const float*)d_in[26];
  const float* f1_bt  = (const float*)d_in[27];
  const float* f2_W   = (const float*)d_in[28];
  const float* f2_b   = (const float*)d_in[29];
  const float* f2_g   = (const float*)d_in[30];
  const float* f2_bt  = (const float*)d_in[31];
  const float* f3_W   = (const float*)d_in[32];
  const float* f3_b   = (const float*)d_in[33];
  const float* f3_g   = (const float*)d_in[34];
  const float* f3_bt  = (const float*)d_in[35];
  const float* fo_W   = (const float*)d_in[36];
  const float* fo_b   = (const float*)d_in[37];
  const int* srcI = ei;
  const int* dstI = ei + E_;

  char* base = (char*)d_ws;
  size_t off = 0;
  auto alloc = [&](size_t bytes) -> void* {
    off = (off + 255) & ~(size_t)255;
    void* p = base + off;
    off += bytes;
    return p;
  };
  float* t0    = (float*)alloc((size_t)N_ * 64 * 4);
  float* t1    = (float*)alloc((size_t)E_ * 128 * 4);
  float* x0    = (float*)alloc((size_t)N_ * 64 * 4);
  float* hb    = (float*)alloc((size_t)N_ * 64 * 4);
  _Float16* ehq = (_Float16*)alloc((size_t)E_ * 128 * 2);
  half8* w2p8  = (half8*)alloc((size_t)65536 * 16);
  half8* pWih  = (half8*)alloc((size_t)1536 * 16);
  half8* pWhh  = (half8*)alloc((size_t)1536 * 16);
  half8* pE2R  = (half8*)alloc((size_t)1024 * 16);
  float* P2    = (float*)alloc((size_t)N_ * 64 * 4);
  float* R     = (float*)alloc((size_t)N_ * 64 * 4);
  float* msg   = (float*)alloc((size_t)E_ * 64 * 4);
  int* cnt_i   = (int*)alloc((size_t)N_ * 4);
  int* cursor  = (int*)alloc((size_t)N_ * 4);
  int* row_start = (int*)alloc((size_t)(N_ + 1) * 4);
  int* csr     = (int*)alloc((size_t)E_ * 4);
  float* cntf  = (float*)alloc((size_t)N_ * 4);
  int* nodecnt = (int*)alloc(64 * 4);
  int* gs      = (int*)alloc(65 * 4);
  float* mean0 = (float*)alloc(64 * 4);
  float* rstd0 = (float*)alloc(64 * 4);
  float* meanE = (float*)alloc(128 * 4);
  float* rstdE = (float*)alloc(128 * 4);
  float* pT    = (float*)alloc((size_t)16 * 128 * 4);
  float* pE    = (float*)alloc((size_t)256 * 256 * 4);
  float* qs    = (float*)alloc((size_t)B_ * 128 * 4);
  float* y1    = (float*)alloc((size_t)B_ * 256 * 4);
  float* y2    = (float*)alloc((size_t)B_ * 128 * 4);

  hipMemsetAsync(cnt_i, 0, (size_t)N_ * 4, stream);
  hipMemsetAsync(nodecnt, 0, 64 * 4, stream);

  k_pre1<<<2720, 256, 0, stream>>>(x, lin0_W, lin0_b, eattr, e1_W, e1_b,
                                   dstI, batch, t0, t1, cnt_i, nodecnt);
  k_statsP<<<272, 256, 0, stream>>>(t0, t1, pT, pE);
  k_scans<<<1, 1024, 0, stream>>>(cnt_i, nodecnt, row_start, cursor, cntf, gs,
                                  pT, pE, mean0, rstd0, meanE, rstdE);
  k_pre3<<<2832, 256, 0, stream>>>(t0, mean0, rstd0, bn0_g, bn0_b, x0, hb,
                                   t1, meanE, rstdE, ebn_g, ebn_b, ehq, e2_W, w2p8,
                                   gWih, gWhh, pWih, pWhh, e2_b, root_W, pE2R);
  k_fillnl<<<2176, 256, 0, stream>>>(dstI, cursor, csr, x0, e2_b, root_W, root_b, P2, R);

  for (int s = 0; s < 4; ++s) {
    k_msg<<<E_ / 64, 256, 0, stream>>>(ehq, w2p8, (s == 0) ? x0 : hb, P2, srcI, msg);
    k_node<<<N_ / 16, 256, 0, stream>>>(msg, csr, row_start, cntf,
                                        pWih, pWhh, gbih, gbhh, pE2R, root_b,
                                        hb, P2, R, (s < 3) ? 1 : 0);
  }

  k_s2s<<<B_, 256, 0, stream>>>(hb, gs, lWih, lWhh, lbih, lbhh, qs);
  k_fc<<<64, 256, 0, stream>>>(qs, f1_W, f1_b, f1_g, f1_bt, y1, 128, 256);
  k_fc<<<32, 256, 0, stream>>>(y1, f2_W, f2_b, f2_g, f2_bt, y2, 256, 128);
  k_f3fo<<<1, 256, 0, stream>>>(y2, f3_W, f3_b, f3_g, f3_bt, fo_W, fo_b, (float*)d_out);
}